// Round 7
// baseline (371.360 us; speedup 1.0000x reference)
//
#include <hip/hip_runtime.h>
#include <math.h>
#include <stdint.h>

#define NB 32
#define NQ 4000
#define NG 100
#define NC1 4
#define NC2 32
#define NC3 8
#define NCT 44   // NC1+NC2+NC3
#define GCH 25   // g-chunk per cost block (NG/4)
#define SLK 16   // per-column shortlist depth (exact sorted top-SLK by (cost, q))
#define MTH 512  // match_kernel block size (8 waves -> cheaper barriers than 16)

// output layout (floats): m[B,Q,G] | selected[B,Q] | gt_idx[B,Q] | matched_qidx[B,G] | cost[B,Q,G]
static const size_t OFF_M    = 0;
static const size_t OFF_SEL  = (size_t)NB * NQ * NG;          // 12,800,000
static const size_t OFF_GTI  = OFF_SEL + (size_t)NB * NQ;     // 12,928,000
static const size_t OFF_MQ   = OFF_GTI + (size_t)NB * NQ;     // 13,056,000
static const size_t OFF_COST = OFF_MQ + (size_t)NB * NG;      // 13,059,200

__device__ __forceinline__ float focal_diff(float x) {
    float p   = 1.0f / (1.0f + expf(-x));
    float neg = 0.75f * (p * p) * (-logf(1.0f - p + 1e-8f));
    float pos = 0.25f * ((1.0f - p) * (1.0f - p)) * (-logf(p + 1e-8f));
    return pos - neg;
}

__device__ __forceinline__ unsigned ordered_bits(float f) {
    unsigned u = __float_as_uint(f);
    return (u & 0x80000000u) ? ~u : (u | 0x80000000u);
}

// ---------------- focal kernel: FDT[b][c][q] (c-major) via LDS tile transpose ----------------
// FDT scratch now lives in the M-output region (out + OFF_M, 51.2 MB >= 22.5 MB): written here,
// consumed by cost_kernel, overwritten by m_expand_kernel at the very end. (It moved out of the
// cost-output region because cost_kernel now writes OC directly.)
__global__ __launch_bounds__(256) void focal_kernel(
    const float* __restrict__ l1, const float* __restrict__ l2, const float* __restrict__ l3,
    float* __restrict__ FDT)
{
    const int b  = blockIdx.y;
    const int q0 = blockIdx.x * 64;
    const int tid = threadIdx.x;
    __shared__ float tile[64][NCT + 1];   // stride 45 (odd) -> conflict-free column reads

    for (int idx = tid; idx < 64 * NC1; idx += 256) {
        const int qi = idx >> 2, c = idx & 3;
        const int q = q0 + qi;
        if (q < NQ) tile[qi][c] = focal_diff(l1[((size_t)b * NQ + q) * NC1 + c]);
    }
    for (int idx = tid; idx < 64 * NC2; idx += 256) {
        const int qi = idx >> 5, c = idx & 31;
        const int q = q0 + qi;
        if (q < NQ) tile[qi][NC1 + c] = focal_diff(l2[((size_t)b * NQ + q) * NC2 + c]);
    }
    for (int idx = tid; idx < 64 * NC3; idx += 256) {
        const int qi = idx >> 3, c = idx & 7;
        const int q = q0 + qi;
        if (q < NQ) tile[qi][NC1 + NC2 + c] = focal_diff(l3[((size_t)b * NQ + q) * NC3 + c]);
    }
    __syncthreads();

    for (int idx = tid; idx < NCT * 64; idx += 256) {
        const int c = idx >> 6, qi = idx & 63;
        const int q = q0 + qi;
        if (q < NQ) FDT[((size_t)b * NCT + c) * NQ + q] = tile[qi][c];
    }
}

// ---------------- mask kernel: gating masks per (b,q): bm uint4 + fgadd ----------------
__global__ __launch_bounds__(256) void mask_kernel(
    const float* __restrict__ pb, const float* __restrict__ gbx,
    uint4* __restrict__ bmout, float* __restrict__ fgout)
{
    const int b   = blockIdx.y;
    const int tid = threadIdx.x;

    __shared__ float s_ib[NG][4];   // round-tripped xyxy for in_box
    __shared__ float s_ic[NG][4];   // center-radius bounds

    if (tid < NG) {
        const int g = tid;
        const float x0 = gbx[((size_t)b * NG + g) * 4 + 0];
        const float y0 = gbx[((size_t)b * NG + g) * 4 + 1];
        const float x1 = gbx[((size_t)b * NG + g) * 4 + 2];
        const float y1 = gbx[((size_t)b * NG + g) * 4 + 3];
        const float cx = (x0 + x1) * 0.5f, cy = (y0 + y1) * 0.5f;
        const float w0 = x1 - x0, h0 = y1 - y0;
        const float bx0 = cx - 0.5f * w0, bx1 = cx + 0.5f * w0;
        const float by0 = cy - 0.5f * h0, by1 = cy + 0.5f * h0;
        s_ib[g][0] = bx0; s_ib[g][1] = by0; s_ib[g][2] = bx1; s_ib[g][3] = by1;
        const float w = bx1 - bx0, h = by1 - by0;   // reference recomputes w,h from round-tripped xyxy
        s_ic[g][0] = cx - 2.5f * w; s_ic[g][1] = cx + 2.5f * w;
        s_ic[g][2] = cy - 2.5f * h; s_ic[g][3] = cy + 2.5f * h;
    }
    __syncthreads();

    const int q = blockIdx.x * 256 + tid;
    if (q >= NQ) return;

    const float4 pv = reinterpret_cast<const float4*>(pb)[(size_t)b * NQ + q];
    const float ax = (pv.x + pv.z) * 0.5f, ay = (pv.y + pv.w) * 0.5f;

    unsigned bm[4] = {0u, 0u, 0u, 0u};
    bool fg = false;
    for (int g = 0; g < NG; ++g) {
        const bool ib = (ax > s_ib[g][0]) && (ax < s_ib[g][2]) && (ay > s_ib[g][1]) && (ay < s_ib[g][3]);
        const bool ic = (ax > s_ic[g][0]) && (ax < s_ic[g][1]) && (ay > s_ic[g][2]) && (ay < s_ic[g][3]);
        fg = fg || ib || ic;
        if (ib && ic) bm[g >> 5] |= (1u << (g & 31));
    }
    bmout[(size_t)b * NQ + q] = make_uint4(bm[0], bm[1], bm[2], bm[3]);
    fgout[(size_t)b * NQ + q] = fg ? 0.0f : 10000.0f;
}

// ---------------- cost kernel: grid (qblocks, B, 4 g-chunks), one thread per q ----------------
// Round-7 fusion: each thread owns OC[q][g0..g0+24] (100 contiguous bytes of the q-major cost
// output), so it writes the final transposed cost DIRECTLY alongside the g-major costT. This
// removes write_out_kernel's 51.2 MB re-read + transpose pass entirely.
__global__ __launch_bounds__(256) void cost_kernel(
    const float* __restrict__ pb, const float* __restrict__ gbx, const float* __restrict__ img,
    const int* __restrict__ t1, const int* __restrict__ t2, const int* __restrict__ t3,
    const float* __restrict__ FDT, const uint4* __restrict__ bmin, const float* __restrict__ fgin,
    float* __restrict__ costT, float* __restrict__ outc)
{
    const int b   = blockIdx.y;
    const int g0  = blockIdx.z * GCH;
    const int tid = threadIdx.x;

    __shared__ float s_ng[GCH][4];
    __shared__ float s_gx[GCH][4];
    __shared__ float s_ab[GCH];
    __shared__ int   s_lab[GCH][3];
    __shared__ float s_isz[4];

    if (tid < 4) s_isz[tid] = img[b * 4 + tid];
    if (tid < GCH) {
        const int g = g0 + tid;
        const float x0 = gbx[((size_t)b * NG + g) * 4 + 0];
        const float y0 = gbx[((size_t)b * NG + g) * 4 + 1];
        const float x1 = gbx[((size_t)b * NG + g) * 4 + 2];
        const float y1 = gbx[((size_t)b * NG + g) * 4 + 3];
        s_gx[tid][0] = x0; s_gx[tid][1] = y0; s_gx[tid][2] = x1; s_gx[tid][3] = y1;
        s_ab[tid] = (x1 - x0) * (y1 - y0);
        s_ng[tid][0] = x0 / img[b * 4 + 0];
        s_ng[tid][1] = y0 / img[b * 4 + 1];
        s_ng[tid][2] = x1 / img[b * 4 + 2];
        s_ng[tid][3] = y1 / img[b * 4 + 3];
        s_lab[tid][0] = t1[b * NG + g];
        s_lab[tid][1] = NC1 + t2[b * NG + g];
        s_lab[tid][2] = NC1 + NC2 + t3[b * NG + g];
    }
    __syncthreads();

    const int q = blockIdx.x * 256 + tid;
    if (q >= NQ) return;

    const float4 pv = reinterpret_cast<const float4*>(pb)[(size_t)b * NQ + q];
    const float p0 = pv.x, p1 = pv.y, p2 = pv.z, p3 = pv.w;
    const float areaA = (p2 - p0) * (p3 - p1);
    const float n0 = p0 / s_isz[0], n1 = p1 / s_isz[1], n2 = p2 / s_isz[2], n3 = p3 / s_isz[3];

    const uint4 bm4 = bmin[(size_t)b * NQ + q];
    const unsigned bm[4] = {bm4.x, bm4.y, bm4.z, bm4.w};
    const float fgadd = fgin[(size_t)b * NQ + q];

    const float* F = FDT + (size_t)b * NCT * NQ + q;
    float* ct = costT + (size_t)b * NG * NQ + q + (size_t)g0 * NQ;
    float* oc = outc + ((size_t)b * NQ + q) * NG + g0;   // 25 contiguous floats per thread
#pragma unroll 5
    for (int gl = 0; gl < GCH; ++gl) {
        const int g = g0 + gl;
        const float f1 = F[(size_t)s_lab[gl][0] * NQ];
        const float f2 = F[(size_t)s_lab[gl][1] * NQ];
        const float f3 = F[(size_t)s_lab[gl][2] * NQ];
        float cb = fabsf(n0 - s_ng[gl][0]);
        cb = cb + fabsf(n1 - s_ng[gl][1]);
        cb = cb + fabsf(n2 - s_ng[gl][2]);
        cb = cb + fabsf(n3 - s_ng[gl][3]);
        const float gx0 = s_gx[gl][0], gy0 = s_gx[gl][1], gx1 = s_gx[gl][2], gy1 = s_gx[gl][3];
        const float ltx = fmaxf(p0, gx0), lty = fmaxf(p1, gy0);
        const float rbx = fminf(p2, gx1), rby = fminf(p3, gy1);
        const float iw = fmaxf(rbx - ltx, 0.0f), ih = fmaxf(rby - lty, 0.0f);
        const float inter = iw * ih;
        const float uni = areaA + s_ab[gl] - inter;
        const float iou = inter / uni;
        const float ex0 = fminf(p0, gx0), ey0 = fminf(p1, gy0);
        const float ex1 = fmaxf(p2, gx1), ey1 = fmaxf(p3, gy1);
        const float ew = fmaxf(ex1 - ex0, 0.0f), eh = fmaxf(ey1 - ey0, 0.0f);
        const float ea = ew * eh;
        const float giou = iou - (ea - uni) / ea;
        const float cc = (f1 + f2) + f3;
        const bool inbc = (bm[g >> 5] >> (g & 31)) & 1u;
        float cost = cb;
        cost = cost + 0.33333334f * cc;
        cost = cost + (-giou);
        cost = cost + (inbc ? 0.0f : 100.0f);
        cost = cost + fgadd;
        ct[(size_t)gl * NQ] = cost;
        oc[gl] = cost;
    }
}

// ---------------- top-k helpers (validated merge path) ----------------
template <bool MAXSEL>
__device__ __forceinline__ bool better(float av, int ai, float bv, int bi) {
    if (MAXSEL) return (av > bv) || (av == bv && ai < bi);
    else        return (av < bv) || (av == bv && ai < bi);
}

template <bool MAXSEL>
__device__ __forceinline__ void ins5(float (&v)[5], int (&id)[5], float nv, int ni) {
    if (!better<MAXSEL>(nv, ni, v[4], id[4])) return;
    v[4] = nv; id[4] = ni;
#pragma unroll
    for (int j = 4; j > 0; --j) {
        if (better<MAXSEL>(v[j], id[j], v[j - 1], id[j - 1])) {
            float tv = v[j]; v[j] = v[j - 1]; v[j - 1] = tv;
            int   ti = id[j]; id[j] = id[j - 1]; id[j - 1] = ti;
        }
    }
}

template <bool MAXSEL>
__device__ __forceinline__ void merge5(float (&v)[5], int (&id)[5], float (&ov)[5], int (&oi)[5]) {
#pragma unroll
    for (int r = 0; r < 5; ++r) {
        float bv = v[0]; int bi = id[0];
#pragma unroll
        for (int off = 32; off >= 1; off >>= 1) {
            float xv = __shfl_xor(bv, off, 64);
            int   xi = __shfl_xor(bi, off, 64);
            if (better<MAXSEL>(xv, xi, bv, bi)) { bv = xv; bi = xi; }
        }
        ov[r] = bv; oi[r] = bi;
        if (id[0] == bi) {
            v[0] = v[1]; id[0] = id[1];
            v[1] = v[2]; id[1] = id[2];
            v[2] = v[3]; id[2] = id[3];
            v[3] = v[4]; id[3] = id[4];
            v[4] = MAXSEL ? -INFINITY : INFINITY; id[4] = 0x7fffffff;
        }
    }
}

// ---------------- branchless insertion networks (per-lane scan only) ----------------
// strict compares = first-seen-wins on ties; within a lane elements arrive in ascending q,
// so this matches the (value, index) tie rule exactly. Lists stay sorted for the merges.
__device__ __forceinline__ void push_max5i(float (&v)[5], int (&id)[5], float t, int it) {
#pragma unroll
    for (int i = 0; i < 5; ++i) {
        const bool b = t > v[i];
        const float nv = b ? t : v[i];
        const float nt = b ? v[i] : t;
        const int ni  = b ? it : id[i];
        const int nit = b ? id[i] : it;
        v[i] = nv; id[i] = ni; t = nt; it = nit;
    }
}

// ---------------- per-column top-k (4 waves/column) + exact sorted top-16 shortlist ----------------
// Shortlist keys: u64 = (ordered_bits(cost) << 32) | q. ordered_bits is strictly monotone on
// floats, q < 2^32, so u64 '<' == (cost, q) lexicographic — identical tie semantics to the
// validated (value,index) path. Per-lane: Batcher odd-even mergesort of its 16 elements
// (63 compare-exchanges), then a 16-round wave arg-min merge of the 64 sorted lane lists,
// then a tid0 4-way merge across waves.  [ROUND-4 VERSION — kept frozen; micro-variants
// (named scalars, launch-bounds tweaks) measured within or below the ~70-80us noise band.]
#define CHUNK 1000   // NQ / 4

#define CE(i, j) { const unsigned long long _a = kk[i], _b = kk[j]; \
                   const bool _s = _b < _a; \
                   kk[i] = _s ? _b : _a; kk[j] = _s ? _a : _b; }

__global__ __launch_bounds__(256, 2) void col_topk_kernel(
    const float* __restrict__ pb, const float* __restrict__ gbx, const float* __restrict__ costT,
    int* __restrict__ grc, int* __restrict__ grnew, int* __restrict__ grsl)
{
    const int g = blockIdx.x, b = blockIdx.y;
    const int tid = threadIdx.x, lane = tid & 63, wave = tid >> 6;   // 4 waves

    __shared__ float              s_v[4][5];
    __shared__ int                s_i[4][5];
    __shared__ unsigned long long s_ck[4][SLK];

    const float gx0 = gbx[((size_t)b * NG + g) * 4 + 0];
    const float gy0 = gbx[((size_t)b * NG + g) * 4 + 1];
    const float gx1 = gbx[((size_t)b * NG + g) * 4 + 2];
    const float gy1 = gbx[((size_t)b * NG + g) * 4 + 3];
    const float areaB = (gx1 - gx0) * (gy1 - gy0);
    const float4* PB = reinterpret_cast<const float4*>(pb) + (size_t)b * NQ;
    const float* CT = costT + (size_t)b * NG * NQ + (size_t)g * NQ;

    const int q0 = wave * CHUNK;

    // ---- Phase 1: cost top-16 (min, sorted). Load folded directly into key pack. ----
    {
        unsigned long long kk[16];
#pragma unroll
        for (int i = 0; i < 16; ++i) {
            const bool live = (i < 15) || (lane < 40);   // batch 15 covers lanes 0..39 (CHUNK=1000)
            const int q = q0 + i * 64 + lane;
            const float c = live ? CT[q] : 0.0f;
            kk[i] = live ? ((((unsigned long long)ordered_bits(c)) << 32) | (unsigned)q)
                         : ~0ull;
        }

        // Batcher odd-even mergesort, n=16: 63 compare-exchanges, ascending.
        CE(0,1)  CE(2,3)  CE(4,5)  CE(6,7)  CE(8,9)  CE(10,11) CE(12,13) CE(14,15)
        CE(0,2)  CE(1,3)  CE(4,6)  CE(5,7)  CE(8,10) CE(9,11)  CE(12,14) CE(13,15)
        CE(1,2)  CE(5,6)  CE(9,10) CE(13,14)
        CE(0,4)  CE(1,5)  CE(2,6)  CE(3,7)  CE(8,12) CE(9,13)  CE(10,14) CE(11,15)
        CE(2,4)  CE(3,5)  CE(10,12) CE(11,13)
        CE(1,2)  CE(3,4)  CE(5,6)  CE(9,10) CE(11,12) CE(13,14)
        CE(0,8)  CE(1,9)  CE(2,10) CE(3,11) CE(4,12)  CE(5,13)  CE(6,14)  CE(7,15)
        CE(4,8)  CE(5,9)  CE(6,10) CE(7,11)
        CE(2,4)  CE(3,5)  CE(6,8)  CE(7,9)  CE(10,12) CE(11,13)
        CE(1,2)  CE(3,4)  CE(5,6)  CE(7,8)  CE(9,10)  CE(11,12) CE(13,14)

        // 16-round wave arg-min merge of sorted lane lists; lane0 writes sorted wave top-16.
        for (int r = 0; r < SLK; ++r) {
            unsigned long long bk = kk[0];
#pragma unroll
            for (int off = 32; off >= 1; off >>= 1) {
                const unsigned long long xk = __shfl_xor(bk, off, 64);
                if (xk < bk) bk = xk;
            }
            if (lane == 0) s_ck[wave][r] = bk;
            if (kk[0] == bk) {   // winner advances (keys unique for real entries)
#pragma unroll
                for (int j = 0; j < 15; ++j) kk[j] = kk[j + 1];
                kk[15] = ~0ull;
            }
        }
    }

    // ---- Phase 2: IoU top-5 over this wave's chunk (branchless insert; validated path) ----
    {
        const int q1 = q0 + CHUNK;
        float tv[5]; int ti[5];
#pragma unroll
        for (int k = 0; k < 5; ++k) { tv[k] = -INFINITY; ti[k] = 0x7fffffff; }
        for (int base = q0; base < q1; base += 64) {
            const int q = base + lane;
            if (q < q1) {
                const float4 p = PB[q];
                const float ltx = fmaxf(p.x, gx0), lty = fmaxf(p.y, gy0);
                const float rbx = fminf(p.z, gx1), rby = fminf(p.w, gy1);
                const float iw = fmaxf(rbx - ltx, 0.0f), ih = fmaxf(rby - lty, 0.0f);
                const float inter = iw * ih;
                const float areaA = (p.z - p.x) * (p.w - p.y);
                const float uni = areaA + areaB - inter;
                push_max5i(tv, ti, inter / uni, q);
            }
        }
        float ov[5]; int oi[5];
        merge5<true>(tv, ti, ov, oi);
        if (lane == 0) {
#pragma unroll
            for (int k = 0; k < 5; ++k) { s_v[wave][k] = ov[k]; s_i[wave][k] = oi[k]; }
        }
    }
    __syncthreads();

    if (tid == 0) {
        // dynamic_k from IoU top-5
        float tv[5]; int ti[5];
#pragma unroll
        for (int k = 0; k < 5; ++k) { tv[k] = -INFINITY; ti[k] = 0x7fffffff; }
        for (int w = 0; w < 4; ++w)
#pragma unroll
            for (int k = 0; k < 5; ++k) ins5<true>(tv, ti, s_v[w][k], s_i[w][k]);
        const float s = ((((tv[0] + tv[1]) + tv[2]) + tv[3]) + tv[4]);
        int dk = (int)s;   // trunc toward zero, matches astype(int32)
        if (dk < 1) dk = 1;

        // 4-way merge of sorted u64 wave lists -> exact sorted column top-16.
        int h0 = 0, h1 = 0, h2 = 0, h3 = 0;
        int* SL = grsl + ((size_t)b * NG + g) * SLK;
        for (int k = 0; k < SLK; ++k) {
            unsigned long long bk = ~0ull; int bw = 0;
            if (h0 < SLK && s_ck[0][h0] < bk) { bk = s_ck[0][h0]; bw = 0; }
            if (h1 < SLK && s_ck[1][h1] < bk) { bk = s_ck[1][h1]; bw = 1; }
            if (h2 < SLK && s_ck[2][h2] < bk) { bk = s_ck[2][h2]; bw = 2; }
            if (h3 < SLK && s_ck[3][h3] < bk) { bk = s_ck[3][h3]; bw = 3; }
            if (bw == 0) h0++; else if (bw == 1) h1++; else if (bw == 2) h2++; else h3++;
            const int bi = (int)(unsigned)(bk & 0xffffffffull);
            SL[k] = bi;
            if (k < dk) {
                atomicAdd(&grc[b * NQ + bi], 1);
                grnew[b * NQ + bi] = g;   // benign race: only read when grc==1
            }
        }
    }
}

// replicate reference's sequential penalty accumulation rounding
__device__ __forceinline__ float pen_add(float v, int k) {
    while (k-- > 0) v += 100000.0f;
    return v;
}

// ---------------- match kernel: one block per image, incremental worklist version ----------------
// Exactness argument vs the full-sweep version:
//  * Rows never un-match (c>=1 stays). A row's state changes in iteration `it` iff rc[q]>0
//    (it was picked by the previous g-loop). All other rows reproduce rmatch verbatim, so
//    processing ONLY the worklist of picked rows is exact. colc is maintained incrementally
//    (+-1 on match transitions), which equals the full recount.
//  * pen[q] closed form: pen++ ran once per completed iteration for rows matched at that time;
//    a row first matched in iteration t has pen = it - t at q-loop time, it+1 - t at g-loop
//    time, and L - t at output (L = iteration where the zero-column check passed, or 2000).
//  * g-loop fast path: pen[qq]==0  <=>  rmatch[qq] < 0 (matched rows have pen >= 1 there).
//    Fallback full scan reconstructs pen exactly from t_match and uses the same pen_add chain.
// 2 barriers/iter (zero-column collection folded into Phase C via direct colc scan + flag),
// 512-thread block. Termination value L identical: flag==0 <=> zn==0 at the same point.
__global__ __launch_bounds__(MTH) void match_kernel(
    const float* __restrict__ costT, const int* __restrict__ grc, const int* __restrict__ grnew,
    const int* __restrict__ grsl,
    float* __restrict__ out, int* __restrict__ rm_out)
{
    const int b = blockIdx.x, tid = threadIdx.x;
    const int lane = tid & 63, wave = tid >> 6;   // 8 waves

    __shared__ short              rmatch[NQ];
    __shared__ short              rnew[NQ];
    __shared__ short              tmat[NQ];     // iteration of first match (valid iff rmatch>=0)
    __shared__ int                rc[NQ];
    __shared__ int                colc[NG];
    __shared__ unsigned long long colkey[NG];
    __shared__ short              sl[NG * SLK];
    __shared__ short              wl[2][1024];  // double-buffered worklist (seed <= 500, later <= NG)
    __shared__ int                wlc[2];
    __shared__ int                flag;

    const float* CT = costT + (size_t)b * NG * NQ;

    if (tid == 0) { wlc[0] = 0; wlc[1] = 0; }
    if (tid < NG) colc[tid] = 0;
    __syncthreads();

    for (int q = tid; q < NQ; q += MTH) {
        rmatch[q] = -1;
        const int r = grc[b * NQ + q];
        rc[q] = r;
        rnew[q] = (short)grnew[b * NQ + q];
        if (r > 0) { const int i = atomicAdd(&wlc[0], 1); wl[0][i] = (short)q; }
    }
    for (int i = tid; i < NG * SLK; i += MTH) sl[i] = (short)grsl[(size_t)b * NG * SLK + i];
    __syncthreads();

    int L = 2000;
    for (int iter = 0; iter < 2000; ++iter) {
        const int p = iter & 1;
        // ---- Phase A: process this iteration's worklist (dedup via atomicExch) ----
        const int n = wlc[p];
        for (int i = tid; i < n; i += MTH) {
            const int q = (int)wl[p][i];
            const int rcq = atomicExch(&rc[q], 0);
            if (rcq == 0) continue;              // duplicate entry already handled
            const int oldm = rmatch[q];
            const int c = rcq + (oldm >= 0 ? 1 : 0);
            int nm;
            if (c == 1) nm = (int)rnew[q];       // rcq>=1 here, so reference takes rnew
            else {
                const int kp = (oldm >= 0) ? (iter - (int)tmat[q]) : 0;
                float bv = INFINITY; nm = 0;
                for (int g = 0; g < NG; ++g) {
                    const float v = pen_add(CT[(size_t)g * NQ + q], kp);
                    if (v < bv) { bv = v; nm = g; }
                }
            }
            rmatch[q] = (short)nm;
            if (oldm < 0) { tmat[q] = (short)iter; atomicAdd(&colc[nm], 1); }
            else if (oldm != nm) { atomicSub(&colc[oldm], 1); atomicAdd(&colc[nm], 1); }
        }
        if (tid == 0) { wlc[p ^ 1] = 0; flag = 0; }   // wl[p^1]/flag untouched by Phase A
        __syncthreads();

        // ---- Phase C: rematch zero columns (direct colc scan; pen here = iter+1 - tmat) ----
        for (int g = wave; g < NG; g += (MTH / 64)) {
            if (colc[g] != 0) continue;
            if (lane == 0) flag = 1;             // benign multi-write, same value
            // shortlist fast path: first (by sorted (cost,q) order) entry with pen==0
            int cand = -1;
            if (lane < SLK) {
                const int qq = (int)sl[g * SLK + lane];
                if (rmatch[qq] < 0) cand = qq;
            }
            const unsigned long long bal = __ballot(cand >= 0);
            int bi;
            if (bal != 0ull) {
                const int src = __ffsll(bal) - 1;
                bi = __shfl(cand, src, 64);
            } else {
                // fallback: exact full scan with pen_add semantics (rare)
                float bv = INFINITY; bi = 0x7fffffff;
                for (int base = 0; base < NQ; base += 64) {
                    const int q = base + lane;
                    if (q < NQ) {
                        const int kp = (rmatch[q] >= 0) ? (iter + 1 - (int)tmat[q]) : 0;
                        const float v = pen_add(CT[(size_t)g * NQ + q], kp);
                        if (v < bv || (v == bv && q < bi)) { bv = v; bi = q; }
                    }
                }
#pragma unroll
                for (int off = 32; off >= 1; off >>= 1) {
                    const float xv = __shfl_xor(bv, off, 64);
                    const int   xi = __shfl_xor(bi, off, 64);
                    if (xv < bv || (xv == bv && xi < bi)) { bv = xv; bi = xi; }
                }
            }
            if (lane == 0) {
                atomicAdd(&rc[bi], 1);
                rnew[bi] = (short)g;             // benign race: only read when count==1
                const int i = atomicAdd(&wlc[p ^ 1], 1);
                wl[p ^ 1][i] = (short)bi;
            }
        }
        __syncthreads();
        if (!flag) { L = iter; break; }
    }

    // outputs: selected, gt_idx, rm; matched_qidx via per-row atomicMin (ordered-float<<32 | q)
    if (tid < NG) colkey[tid] = ~0ull;
    __syncthreads();
    for (int q = tid; q < NQ; q += MTH) {
        const int m = rmatch[q];
        out[OFF_SEL + (size_t)b * NQ + q] = (m >= 0) ? 1.0f : 0.0f;
        out[OFF_GTI + (size_t)b * NQ + q] = (float)(m >= 0 ? m : 0);
        rm_out[b * NQ + q] = m;
        if (m >= 0) {
            const float v = pen_add(CT[(size_t)m * NQ + q], L - (int)tmat[q]);
            const unsigned long long key = ((unsigned long long)ordered_bits(v) << 32) | (unsigned)q;
            atomicMin(&colkey[m], key);
        }
    }
    __syncthreads();
    if (tid < NG) out[OFF_MQ + (size_t)b * NG + tid] = (float)(unsigned)(colkey[tid] & 0xffffffffull);
}

// ---------------- m-expand: write OM[q][g] = (rm[q]==g) — replaces write_out_kernel ----------------
// One thread per q; writes its 100-float row (400B, 16B-aligned) as 25 float4 stores.
__global__ __launch_bounds__(256) void m_expand_kernel(
    const int* __restrict__ rm, float* __restrict__ out)
{
    const int b = blockIdx.y;
    const int q = blockIdx.x * 256 + threadIdx.x;
    if (q >= NQ) return;
    const int m = rm[b * NQ + q];
    float4* OM = reinterpret_cast<float4*>(out + OFF_M + ((size_t)b * NQ + q) * NG);
#pragma unroll
    for (int j = 0; j < NG / 4; ++j) {
        const int g0 = j * 4;
        float4 v;
        v.x = (m == g0 + 0) ? 1.0f : 0.0f;
        v.y = (m == g0 + 1) ? 1.0f : 0.0f;
        v.z = (m == g0 + 2) ? 1.0f : 0.0f;
        v.w = (m == g0 + 3) ? 1.0f : 0.0f;
        OM[j] = v;
    }
}

extern "C" void kernel_launch(void* const* d_in, const int* in_sizes, int n_in,
                              void* d_out, int out_size, void* d_ws, size_t ws_size,
                              hipStream_t stream)
{
    const float* l1  = (const float*)d_in[0];
    const float* l2  = (const float*)d_in[1];
    const float* l3  = (const float*)d_in[2];
    const float* pb  = (const float*)d_in[3];
    const float* gbx = (const float*)d_in[4];
    const float* img = (const float*)d_in[5];
    const int*   t1  = (const int*)d_in[6];
    const int*   t2  = (const int*)d_in[7];
    const int*   t3  = (const int*)d_in[8];
    float* out = (float*)d_out;

    char* ws = (char*)d_ws;
    float* costT = (float*)ws;                                   ws += (size_t)NB * NG * NQ * sizeof(float); // 51.2 MB
    int*   rm    = (int*)ws;                                     ws += (size_t)NB * NQ * sizeof(int);
    int*   grc   = (int*)ws;                                     ws += (size_t)NB * NQ * sizeof(int);
    int*   grnew = (int*)ws;                                     ws += (size_t)NB * NQ * sizeof(int);
    uint4* bmws  = (uint4*)ws;                                   ws += (size_t)NB * NQ * sizeof(uint4);
    float* fgws  = (float*)ws;                                   ws += (size_t)NB * NQ * sizeof(float);
    int*   grsl  = (int*)ws;                                     // NB*NG*SLK*4 = 204.8 KB

    // FDT scratch lives in the M-output region (out + OFF_M, 51.2 MB >= 22.5 MB): written by
    // focal_kernel, consumed by cost_kernel, overwritten by m_expand_kernel at the end.
    // (cost_kernel now writes the q-major cost output OC = out + OFF_COST directly.)
    float* FDT = out + OFF_M;
    float* OC  = out + OFF_COST;

    hipMemsetAsync(grc, 0, (size_t)NB * NQ * sizeof(int), stream);

    dim3 fg((NQ + 63) / 64, NB);
    focal_kernel<<<fg, 256, 0, stream>>>(l1, l2, l3, FDT);

    dim3 mk((NQ + 255) / 256, NB);
    mask_kernel<<<mk, 256, 0, stream>>>(pb, gbx, bmws, fgws);

    dim3 cg((NQ + 255) / 256, NB, 4);
    cost_kernel<<<cg, 256, 0, stream>>>(pb, gbx, img, t1, t2, t3, FDT, bmws, fgws, costT, OC);

    dim3 kg(NG, NB);
    col_topk_kernel<<<kg, 256, 0, stream>>>(pb, gbx, costT, grc, grnew, grsl);

    match_kernel<<<NB, MTH, 0, stream>>>(costT, grc, grnew, grsl, out, rm);

    dim3 wg((NQ + 255) / 256, NB);
    m_expand_kernel<<<wg, 256, 0, stream>>>(rm, out);
}

// Round 8
// 313.533 us; speedup vs baseline: 1.1844x; 1.1844x over previous
//
#include <hip/hip_runtime.h>
#include <math.h>
#include <stdint.h>

#define NB 32
#define NQ 4000
#define NG 100
#define NC1 4
#define NC2 32
#define NC3 8
#define NCT 44   // NC1+NC2+NC3
#define SLK 16   // per-column shortlist depth (exact sorted top-SLK by (cost, q))
#define MTH 512  // match_kernel block size (8 waves -> cheaper barriers than 16)
#define QB  128  // cost_kernel q-rows per block

// output layout (floats): m[B,Q,G] | selected[B,Q] | gt_idx[B,Q] | matched_qidx[B,G] | cost[B,Q,G]
static const size_t OFF_M    = 0;
static const size_t OFF_SEL  = (size_t)NB * NQ * NG;          // 12,800,000
static const size_t OFF_GTI  = OFF_SEL + (size_t)NB * NQ;     // 12,928,000
static const size_t OFF_MQ   = OFF_GTI + (size_t)NB * NQ;     // 13,056,000
static const size_t OFF_COST = OFF_MQ + (size_t)NB * NG;      // 13,059,200

__device__ __forceinline__ float focal_diff(float x) {
    float p   = 1.0f / (1.0f + expf(-x));
    float neg = 0.75f * (p * p) * (-logf(1.0f - p + 1e-8f));
    float pos = 0.25f * ((1.0f - p) * (1.0f - p)) * (-logf(p + 1e-8f));
    return pos - neg;
}

__device__ __forceinline__ unsigned ordered_bits(float f) {
    unsigned u = __float_as_uint(f);
    return (u & 0x80000000u) ? ~u : (u | 0x80000000u);
}

// ---------------- focal kernel: FDT[b][c][q] (c-major) via LDS tile transpose ----------------
// FDT scratch lives in the M-output region (out + OFF_M, 51.2 MB >= 22.5 MB): written here,
// consumed by cost_kernel, overwritten by m_expand_kernel at the very end.
__global__ __launch_bounds__(256) void focal_kernel(
    const float* __restrict__ l1, const float* __restrict__ l2, const float* __restrict__ l3,
    float* __restrict__ FDT)
{
    const int b  = blockIdx.y;
    const int q0 = blockIdx.x * 64;
    const int tid = threadIdx.x;
    __shared__ float tile[64][NCT + 1];   // stride 45 (odd) -> conflict-free column reads

    for (int idx = tid; idx < 64 * NC1; idx += 256) {
        const int qi = idx >> 2, c = idx & 3;
        const int q = q0 + qi;
        if (q < NQ) tile[qi][c] = focal_diff(l1[((size_t)b * NQ + q) * NC1 + c]);
    }
    for (int idx = tid; idx < 64 * NC2; idx += 256) {
        const int qi = idx >> 5, c = idx & 31;
        const int q = q0 + qi;
        if (q < NQ) tile[qi][NC1 + c] = focal_diff(l2[((size_t)b * NQ + q) * NC2 + c]);
    }
    for (int idx = tid; idx < 64 * NC3; idx += 256) {
        const int qi = idx >> 3, c = idx & 7;
        const int q = q0 + qi;
        if (q < NQ) tile[qi][NC1 + NC2 + c] = focal_diff(l3[((size_t)b * NQ + q) * NC3 + c]);
    }
    __syncthreads();

    for (int idx = tid; idx < NCT * 64; idx += 256) {
        const int c = idx >> 6, qi = idx & 63;
        const int q = q0 + qi;
        if (q < NQ) FDT[((size_t)b * NCT + c) * NQ + q] = tile[qi][c];
    }
}

// ---------------- mask kernel: gating masks per (b,q): bm uint4 + fgadd ----------------
__global__ __launch_bounds__(256) void mask_kernel(
    const float* __restrict__ pb, const float* __restrict__ gbx,
    uint4* __restrict__ bmout, float* __restrict__ fgout)
{
    const int b   = blockIdx.y;
    const int tid = threadIdx.x;

    __shared__ float s_ib[NG][4];   // round-tripped xyxy for in_box
    __shared__ float s_ic[NG][4];   // center-radius bounds

    if (tid < NG) {
        const int g = tid;
        const float x0 = gbx[((size_t)b * NG + g) * 4 + 0];
        const float y0 = gbx[((size_t)b * NG + g) * 4 + 1];
        const float x1 = gbx[((size_t)b * NG + g) * 4 + 2];
        const float y1 = gbx[((size_t)b * NG + g) * 4 + 3];
        const float cx = (x0 + x1) * 0.5f, cy = (y0 + y1) * 0.5f;
        const float w0 = x1 - x0, h0 = y1 - y0;
        const float bx0 = cx - 0.5f * w0, bx1 = cx + 0.5f * w0;
        const float by0 = cy - 0.5f * h0, by1 = cy + 0.5f * h0;
        s_ib[g][0] = bx0; s_ib[g][1] = by0; s_ib[g][2] = bx1; s_ib[g][3] = by1;
        const float w = bx1 - bx0, h = by1 - by0;   // reference recomputes w,h from round-tripped xyxy
        s_ic[g][0] = cx - 2.5f * w; s_ic[g][1] = cx + 2.5f * w;
        s_ic[g][2] = cy - 2.5f * h; s_ic[g][3] = cy + 2.5f * h;
    }
    __syncthreads();

    const int q = blockIdx.x * 256 + tid;
    if (q >= NQ) return;

    const float4 pv = reinterpret_cast<const float4*>(pb)[(size_t)b * NQ + q];
    const float ax = (pv.x + pv.z) * 0.5f, ay = (pv.y + pv.w) * 0.5f;

    unsigned bm[4] = {0u, 0u, 0u, 0u};
    bool fg = false;
    for (int g = 0; g < NG; ++g) {
        const bool ib = (ax > s_ib[g][0]) && (ax < s_ib[g][2]) && (ay > s_ib[g][1]) && (ay < s_ib[g][3]);
        const bool ic = (ax > s_ic[g][0]) && (ax < s_ic[g][1]) && (ay > s_ic[g][2]) && (ay < s_ic[g][3]);
        fg = fg || ib || ic;
        if (ib && ic) bm[g >> 5] |= (1u << (g & 31));
    }
    bmout[(size_t)b * NQ + q] = make_uint4(bm[0], bm[1], bm[2], bm[3]);
    fgout[(size_t)b * NQ + q] = fg ? 0.0f : 10000.0f;
}

// ---------------- cost kernel: grid (NQ/QB, B), in-kernel LDS transpose for OC ----------------
// Round-8: fusion kept, coalescing restored. Thread (qi = tid&127, half = tid>>7) computes
// g in [half*50, half*50+50) for q = q0+qi. costT (g-major) writes are per-g lane-coalesced
// (consecutive q). Each cost also lands in tile[128][101] (pad -> bank (5*qi+g)%32, 2-way =
// free); after one barrier the block streams 128 FULL 400B rows of OC as float4 — fully
// coalesced, no partial cache lines (round-7's 4B@400B-stride scatter caused 273MB writes).
__global__ __launch_bounds__(256) void cost_kernel(
    const float* __restrict__ pb, const float* __restrict__ gbx, const float* __restrict__ img,
    const int* __restrict__ t1, const int* __restrict__ t2, const int* __restrict__ t3,
    const float* __restrict__ FDT, const uint4* __restrict__ bmin, const float* __restrict__ fgin,
    float* __restrict__ costT, float* __restrict__ outc)
{
    const int b   = blockIdx.y;
    const int q0  = blockIdx.x * QB;
    const int tid = threadIdx.x;
    const int qi  = tid & (QB - 1);
    const int hf  = tid >> 7;            // 0: g in [0,50), 1: g in [50,100)

    __shared__ float s_ng[NG][4];
    __shared__ float s_gx[NG][4];
    __shared__ float s_ab[NG];
    __shared__ int   s_lab[NG][3];
    __shared__ float s_isz[4];
    __shared__ float tile[QB][NG + 1];   // pad 101: LDS write bank = (5*qi+g)%32 -> 2-way, free

    if (tid < 4) s_isz[tid] = img[b * 4 + tid];
    if (tid < NG) {
        const int g = tid;
        const float x0 = gbx[((size_t)b * NG + g) * 4 + 0];
        const float y0 = gbx[((size_t)b * NG + g) * 4 + 1];
        const float x1 = gbx[((size_t)b * NG + g) * 4 + 2];
        const float y1 = gbx[((size_t)b * NG + g) * 4 + 3];
        s_gx[g][0] = x0; s_gx[g][1] = y0; s_gx[g][2] = x1; s_gx[g][3] = y1;
        s_ab[g] = (x1 - x0) * (y1 - y0);
        s_ng[g][0] = x0 / img[b * 4 + 0];
        s_ng[g][1] = y0 / img[b * 4 + 1];
        s_ng[g][2] = x1 / img[b * 4 + 2];
        s_ng[g][3] = y1 / img[b * 4 + 3];
        s_lab[g][0] = t1[b * NG + g];
        s_lab[g][1] = NC1 + t2[b * NG + g];
        s_lab[g][2] = NC1 + NC2 + t3[b * NG + g];
    }
    __syncthreads();

    const int q = q0 + qi;
    if (q < NQ) {
        const float4 pv = reinterpret_cast<const float4*>(pb)[(size_t)b * NQ + q];
        const float p0 = pv.x, p1 = pv.y, p2 = pv.z, p3 = pv.w;
        const float areaA = (p2 - p0) * (p3 - p1);
        const float n0 = p0 / s_isz[0], n1 = p1 / s_isz[1], n2 = p2 / s_isz[2], n3 = p3 / s_isz[3];

        const uint4 bm4 = bmin[(size_t)b * NQ + q];
        const unsigned bm[4] = {bm4.x, bm4.y, bm4.z, bm4.w};
        const float fgadd = fgin[(size_t)b * NQ + q];

        const float* F = FDT + (size_t)b * NCT * NQ + q;
        float* ct = costT + (size_t)b * NG * NQ + q;
        const int gbeg = hf * (NG / 2);
#pragma unroll 5
        for (int gl = 0; gl < NG / 2; ++gl) {
            const int g = gbeg + gl;
            const float f1 = F[(size_t)s_lab[g][0] * NQ];
            const float f2 = F[(size_t)s_lab[g][1] * NQ];
            const float f3 = F[(size_t)s_lab[g][2] * NQ];
            float cb = fabsf(n0 - s_ng[g][0]);
            cb = cb + fabsf(n1 - s_ng[g][1]);
            cb = cb + fabsf(n2 - s_ng[g][2]);
            cb = cb + fabsf(n3 - s_ng[g][3]);
            const float gx0 = s_gx[g][0], gy0 = s_gx[g][1], gx1 = s_gx[g][2], gy1 = s_gx[g][3];
            const float ltx = fmaxf(p0, gx0), lty = fmaxf(p1, gy0);
            const float rbx = fminf(p2, gx1), rby = fminf(p3, gy1);
            const float iw = fmaxf(rbx - ltx, 0.0f), ih = fmaxf(rby - lty, 0.0f);
            const float inter = iw * ih;
            const float uni = areaA + s_ab[g] - inter;
            const float iou = inter / uni;
            const float ex0 = fminf(p0, gx0), ey0 = fminf(p1, gy0);
            const float ex1 = fmaxf(p2, gx1), ey1 = fmaxf(p3, gy1);
            const float ew = fmaxf(ex1 - ex0, 0.0f), eh = fmaxf(ey1 - ey0, 0.0f);
            const float ea = ew * eh;
            const float giou = iou - (ea - uni) / ea;
            const float cc = (f1 + f2) + f3;
            const bool inbc = (bm[g >> 5] >> (g & 31)) & 1u;
            float cost = cb;
            cost = cost + 0.33333334f * cc;
            cost = cost + (-giou);
            cost = cost + (inbc ? 0.0f : 100.0f);
            cost = cost + fgadd;
            ct[(size_t)g * NQ] = cost;   // g-major: lanes (consec q) coalesced per g
            tile[qi][g] = cost;
        }
    }
    __syncthreads();

    // coalesced q-major OC write: full contiguous rows [q0, q0+nrows) x 100 floats
    const int nrows = (NQ - q0 < QB) ? (NQ - q0) : QB;
    float4* OCb = reinterpret_cast<float4*>(outc + ((size_t)b * NQ + q0) * NG);
    for (int idx = tid; idx < nrows * (NG / 4); idx += 256) {
        const int r = idx / (NG / 4), j = idx - r * (NG / 4);
        float4 v;
        v.x = tile[r][4 * j + 0];
        v.y = tile[r][4 * j + 1];
        v.z = tile[r][4 * j + 2];
        v.w = tile[r][4 * j + 3];
        OCb[(size_t)r * (NG / 4) + j] = v;
    }
}

// ---------------- top-k helpers (validated merge path) ----------------
template <bool MAXSEL>
__device__ __forceinline__ bool better(float av, int ai, float bv, int bi) {
    if (MAXSEL) return (av > bv) || (av == bv && ai < bi);
    else        return (av < bv) || (av == bv && ai < bi);
}

template <bool MAXSEL>
__device__ __forceinline__ void ins5(float (&v)[5], int (&id)[5], float nv, int ni) {
    if (!better<MAXSEL>(nv, ni, v[4], id[4])) return;
    v[4] = nv; id[4] = ni;
#pragma unroll
    for (int j = 4; j > 0; --j) {
        if (better<MAXSEL>(v[j], id[j], v[j - 1], id[j - 1])) {
            float tv = v[j]; v[j] = v[j - 1]; v[j - 1] = tv;
            int   ti = id[j]; id[j] = id[j - 1]; id[j - 1] = ti;
        }
    }
}

template <bool MAXSEL>
__device__ __forceinline__ void merge5(float (&v)[5], int (&id)[5], float (&ov)[5], int (&oi)[5]) {
#pragma unroll
    for (int r = 0; r < 5; ++r) {
        float bv = v[0]; int bi = id[0];
#pragma unroll
        for (int off = 32; off >= 1; off >>= 1) {
            float xv = __shfl_xor(bv, off, 64);
            int   xi = __shfl_xor(bi, off, 64);
            if (better<MAXSEL>(xv, xi, bv, bi)) { bv = xv; bi = xi; }
        }
        ov[r] = bv; oi[r] = bi;
        if (id[0] == bi) {
            v[0] = v[1]; id[0] = id[1];
            v[1] = v[2]; id[1] = id[2];
            v[2] = v[3]; id[2] = id[3];
            v[3] = v[4]; id[3] = id[4];
            v[4] = MAXSEL ? -INFINITY : INFINITY; id[4] = 0x7fffffff;
        }
    }
}

// ---------------- branchless insertion networks (per-lane scan only) ----------------
// strict compares = first-seen-wins on ties; within a lane elements arrive in ascending q,
// so this matches the (value, index) tie rule exactly. Lists stay sorted for the merges.
__device__ __forceinline__ void push_max5i(float (&v)[5], int (&id)[5], float t, int it) {
#pragma unroll
    for (int i = 0; i < 5; ++i) {
        const bool b = t > v[i];
        const float nv = b ? t : v[i];
        const float nt = b ? v[i] : t;
        const int ni  = b ? it : id[i];
        const int nit = b ? id[i] : it;
        v[i] = nv; id[i] = ni; t = nt; it = nit;
    }
}

// ---------------- per-column top-k (4 waves/column) + exact sorted top-16 shortlist ----------------
// Shortlist keys: u64 = (ordered_bits(cost) << 32) | q. ordered_bits is strictly monotone on
// floats, q < 2^32, so u64 '<' == (cost, q) lexicographic — identical tie semantics to the
// validated (value,index) path. Per-lane: Batcher odd-even mergesort of its 16 elements
// (63 compare-exchanges), then a 16-round wave arg-min merge of the 64 sorted lane lists,
// then a tid0 4-way merge across waves.  [ROUND-4 VERSION — kept frozen; micro-variants
// measured within or below the ~70-80us noise band.]
#define CHUNK 1000   // NQ / 4

#define CE(i, j) { const unsigned long long _a = kk[i], _b = kk[j]; \
                   const bool _s = _b < _a; \
                   kk[i] = _s ? _b : _a; kk[j] = _s ? _a : _b; }

__global__ __launch_bounds__(256, 2) void col_topk_kernel(
    const float* __restrict__ pb, const float* __restrict__ gbx, const float* __restrict__ costT,
    int* __restrict__ grc, int* __restrict__ grnew, int* __restrict__ grsl)
{
    const int g = blockIdx.x, b = blockIdx.y;
    const int tid = threadIdx.x, lane = tid & 63, wave = tid >> 6;   // 4 waves

    __shared__ float              s_v[4][5];
    __shared__ int                s_i[4][5];
    __shared__ unsigned long long s_ck[4][SLK];

    const float gx0 = gbx[((size_t)b * NG + g) * 4 + 0];
    const float gy0 = gbx[((size_t)b * NG + g) * 4 + 1];
    const float gx1 = gbx[((size_t)b * NG + g) * 4 + 2];
    const float gy1 = gbx[((size_t)b * NG + g) * 4 + 3];
    const float areaB = (gx1 - gx0) * (gy1 - gy0);
    const float4* PB = reinterpret_cast<const float4*>(pb) + (size_t)b * NQ;
    const float* CT = costT + (size_t)b * NG * NQ + (size_t)g * NQ;

    const int q0 = wave * CHUNK;

    // ---- Phase 1: cost top-16 (min, sorted). Load folded directly into key pack. ----
    {
        unsigned long long kk[16];
#pragma unroll
        for (int i = 0; i < 16; ++i) {
            const bool live = (i < 15) || (lane < 40);   // batch 15 covers lanes 0..39 (CHUNK=1000)
            const int q = q0 + i * 64 + lane;
            const float c = live ? CT[q] : 0.0f;
            kk[i] = live ? ((((unsigned long long)ordered_bits(c)) << 32) | (unsigned)q)
                         : ~0ull;
        }

        // Batcher odd-even mergesort, n=16: 63 compare-exchanges, ascending.
        CE(0,1)  CE(2,3)  CE(4,5)  CE(6,7)  CE(8,9)  CE(10,11) CE(12,13) CE(14,15)
        CE(0,2)  CE(1,3)  CE(4,6)  CE(5,7)  CE(8,10) CE(9,11)  CE(12,14) CE(13,15)
        CE(1,2)  CE(5,6)  CE(9,10) CE(13,14)
        CE(0,4)  CE(1,5)  CE(2,6)  CE(3,7)  CE(8,12) CE(9,13)  CE(10,14) CE(11,15)
        CE(2,4)  CE(3,5)  CE(10,12) CE(11,13)
        CE(1,2)  CE(3,4)  CE(5,6)  CE(9,10) CE(11,12) CE(13,14)
        CE(0,8)  CE(1,9)  CE(2,10) CE(3,11) CE(4,12)  CE(5,13)  CE(6,14)  CE(7,15)
        CE(4,8)  CE(5,9)  CE(6,10) CE(7,11)
        CE(2,4)  CE(3,5)  CE(6,8)  CE(7,9)  CE(10,12) CE(11,13)
        CE(1,2)  CE(3,4)  CE(5,6)  CE(7,8)  CE(9,10)  CE(11,12) CE(13,14)

        // 16-round wave arg-min merge of sorted lane lists; lane0 writes sorted wave top-16.
        for (int r = 0; r < SLK; ++r) {
            unsigned long long bk = kk[0];
#pragma unroll
            for (int off = 32; off >= 1; off >>= 1) {
                const unsigned long long xk = __shfl_xor(bk, off, 64);
                if (xk < bk) bk = xk;
            }
            if (lane == 0) s_ck[wave][r] = bk;
            if (kk[0] == bk) {   // winner advances (keys unique for real entries)
#pragma unroll
                for (int j = 0; j < 15; ++j) kk[j] = kk[j + 1];
                kk[15] = ~0ull;
            }
        }
    }

    // ---- Phase 2: IoU top-5 over this wave's chunk (branchless insert; validated path) ----
    {
        const int q1 = q0 + CHUNK;
        float tv[5]; int ti[5];
#pragma unroll
        for (int k = 0; k < 5; ++k) { tv[k] = -INFINITY; ti[k] = 0x7fffffff; }
        for (int base = q0; base < q1; base += 64) {
            const int q = base + lane;
            if (q < q1) {
                const float4 p = PB[q];
                const float ltx = fmaxf(p.x, gx0), lty = fmaxf(p.y, gy0);
                const float rbx = fminf(p.z, gx1), rby = fminf(p.w, gy1);
                const float iw = fmaxf(rbx - ltx, 0.0f), ih = fmaxf(rby - lty, 0.0f);
                const float inter = iw * ih;
                const float areaA = (p.z - p.x) * (p.w - p.y);
                const float uni = areaA + areaB - inter;
                push_max5i(tv, ti, inter / uni, q);
            }
        }
        float ov[5]; int oi[5];
        merge5<true>(tv, ti, ov, oi);
        if (lane == 0) {
#pragma unroll
            for (int k = 0; k < 5; ++k) { s_v[wave][k] = ov[k]; s_i[wave][k] = oi[k]; }
        }
    }
    __syncthreads();

    if (tid == 0) {
        // dynamic_k from IoU top-5
        float tv[5]; int ti[5];
#pragma unroll
        for (int k = 0; k < 5; ++k) { tv[k] = -INFINITY; ti[k] = 0x7fffffff; }
        for (int w = 0; w < 4; ++w)
#pragma unroll
            for (int k = 0; k < 5; ++k) ins5<true>(tv, ti, s_v[w][k], s_i[w][k]);
        const float s = ((((tv[0] + tv[1]) + tv[2]) + tv[3]) + tv[4]);
        int dk = (int)s;   // trunc toward zero, matches astype(int32)
        if (dk < 1) dk = 1;

        // 4-way merge of sorted u64 wave lists -> exact sorted column top-16.
        int h0 = 0, h1 = 0, h2 = 0, h3 = 0;
        int* SL = grsl + ((size_t)b * NG + g) * SLK;
        for (int k = 0; k < SLK; ++k) {
            unsigned long long bk = ~0ull; int bw = 0;
            if (h0 < SLK && s_ck[0][h0] < bk) { bk = s_ck[0][h0]; bw = 0; }
            if (h1 < SLK && s_ck[1][h1] < bk) { bk = s_ck[1][h1]; bw = 1; }
            if (h2 < SLK && s_ck[2][h2] < bk) { bk = s_ck[2][h2]; bw = 2; }
            if (h3 < SLK && s_ck[3][h3] < bk) { bk = s_ck[3][h3]; bw = 3; }
            if (bw == 0) h0++; else if (bw == 1) h1++; else if (bw == 2) h2++; else h3++;
            const int bi = (int)(unsigned)(bk & 0xffffffffull);
            SL[k] = bi;
            if (k < dk) {
                atomicAdd(&grc[b * NQ + bi], 1);
                grnew[b * NQ + bi] = g;   // benign race: only read when grc==1
            }
        }
    }
}

// replicate reference's sequential penalty accumulation rounding
__device__ __forceinline__ float pen_add(float v, int k) {
    while (k-- > 0) v += 100000.0f;
    return v;
}

// ---------------- match kernel: one block per image, incremental worklist version ----------------
// Exactness argument vs the full-sweep version:
//  * Rows never un-match (c>=1 stays). A row's state changes in iteration `it` iff rc[q]>0
//    (it was picked by the previous g-loop). All other rows reproduce rmatch verbatim, so
//    processing ONLY the worklist of picked rows is exact. colc is maintained incrementally
//    (+-1 on match transitions), which equals the full recount.
//  * pen[q] closed form: pen++ ran once per completed iteration for rows matched at that time;
//    a row first matched in iteration t has pen = it - t at q-loop time, it+1 - t at g-loop
//    time, and L - t at output (L = iteration where the zero-column check passed, or 2000).
//  * g-loop fast path: pen[qq]==0  <=>  rmatch[qq] < 0 (matched rows have pen >= 1 there).
//    Fallback full scan reconstructs pen exactly from t_match and uses the same pen_add chain.
// 2 barriers/iter (zero-column collection folded into Phase C via direct colc scan + flag),
// 512-thread block. Termination value L identical: flag==0 <=> zn==0 at the same point.
__global__ __launch_bounds__(MTH) void match_kernel(
    const float* __restrict__ costT, const int* __restrict__ grc, const int* __restrict__ grnew,
    const int* __restrict__ grsl,
    float* __restrict__ out, int* __restrict__ rm_out)
{
    const int b = blockIdx.x, tid = threadIdx.x;
    const int lane = tid & 63, wave = tid >> 6;   // 8 waves

    __shared__ short              rmatch[NQ];
    __shared__ short              rnew[NQ];
    __shared__ short              tmat[NQ];     // iteration of first match (valid iff rmatch>=0)
    __shared__ int                rc[NQ];
    __shared__ int                colc[NG];
    __shared__ unsigned long long colkey[NG];
    __shared__ short              sl[NG * SLK];
    __shared__ short              wl[2][1024];  // double-buffered worklist (seed <= 500, later <= NG)
    __shared__ int                wlc[2];
    __shared__ int                flag;

    const float* CT = costT + (size_t)b * NG * NQ;

    if (tid == 0) { wlc[0] = 0; wlc[1] = 0; }
    if (tid < NG) colc[tid] = 0;
    __syncthreads();

    for (int q = tid; q < NQ; q += MTH) {
        rmatch[q] = -1;
        const int r = grc[b * NQ + q];
        rc[q] = r;
        rnew[q] = (short)grnew[b * NQ + q];
        if (r > 0) { const int i = atomicAdd(&wlc[0], 1); wl[0][i] = (short)q; }
    }
    for (int i = tid; i < NG * SLK; i += MTH) sl[i] = (short)grsl[(size_t)b * NG * SLK + i];
    __syncthreads();

    int L = 2000;
    for (int iter = 0; iter < 2000; ++iter) {
        const int p = iter & 1;
        // ---- Phase A: process this iteration's worklist (dedup via atomicExch) ----
        const int n = wlc[p];
        for (int i = tid; i < n; i += MTH) {
            const int q = (int)wl[p][i];
            const int rcq = atomicExch(&rc[q], 0);
            if (rcq == 0) continue;              // duplicate entry already handled
            const int oldm = rmatch[q];
            const int c = rcq + (oldm >= 0 ? 1 : 0);
            int nm;
            if (c == 1) nm = (int)rnew[q];       // rcq>=1 here, so reference takes rnew
            else {
                const int kp = (oldm >= 0) ? (iter - (int)tmat[q]) : 0;
                float bv = INFINITY; nm = 0;
                for (int g = 0; g < NG; ++g) {
                    const float v = pen_add(CT[(size_t)g * NQ + q], kp);
                    if (v < bv) { bv = v; nm = g; }
                }
            }
            rmatch[q] = (short)nm;
            if (oldm < 0) { tmat[q] = (short)iter; atomicAdd(&colc[nm], 1); }
            else if (oldm != nm) { atomicSub(&colc[oldm], 1); atomicAdd(&colc[nm], 1); }
        }
        if (tid == 0) { wlc[p ^ 1] = 0; flag = 0; }   // wl[p^1]/flag untouched by Phase A
        __syncthreads();

        // ---- Phase C: rematch zero columns (direct colc scan; pen here = iter+1 - tmat) ----
        for (int g = wave; g < NG; g += (MTH / 64)) {
            if (colc[g] != 0) continue;
            if (lane == 0) flag = 1;             // benign multi-write, same value
            // shortlist fast path: first (by sorted (cost,q) order) entry with pen==0
            int cand = -1;
            if (lane < SLK) {
                const int qq = (int)sl[g * SLK + lane];
                if (rmatch[qq] < 0) cand = qq;
            }
            const unsigned long long bal = __ballot(cand >= 0);
            int bi;
            if (bal != 0ull) {
                const int src = __ffsll(bal) - 1;
                bi = __shfl(cand, src, 64);
            } else {
                // fallback: exact full scan with pen_add semantics (rare)
                float bv = INFINITY; bi = 0x7fffffff;
                for (int base = 0; base < NQ; base += 64) {
                    const int q = base + lane;
                    if (q < NQ) {
                        const int kp = (rmatch[q] >= 0) ? (iter + 1 - (int)tmat[q]) : 0;
                        const float v = pen_add(CT[(size_t)g * NQ + q], kp);
                        if (v < bv || (v == bv && q < bi)) { bv = v; bi = q; }
                    }
                }
#pragma unroll
                for (int off = 32; off >= 1; off >>= 1) {
                    const float xv = __shfl_xor(bv, off, 64);
                    const int   xi = __shfl_xor(bi, off, 64);
                    if (xv < bv || (xv == bv && xi < bi)) { bv = xv; bi = xi; }
                }
            }
            if (lane == 0) {
                atomicAdd(&rc[bi], 1);
                rnew[bi] = (short)g;             // benign race: only read when count==1
                const int i = atomicAdd(&wlc[p ^ 1], 1);
                wl[p ^ 1][i] = (short)bi;
            }
        }
        __syncthreads();
        if (!flag) { L = iter; break; }
    }

    // outputs: selected, gt_idx, rm; matched_qidx via per-row atomicMin (ordered-float<<32 | q)
    if (tid < NG) colkey[tid] = ~0ull;
    __syncthreads();
    for (int q = tid; q < NQ; q += MTH) {
        const int m = rmatch[q];
        out[OFF_SEL + (size_t)b * NQ + q] = (m >= 0) ? 1.0f : 0.0f;
        out[OFF_GTI + (size_t)b * NQ + q] = (float)(m >= 0 ? m : 0);
        rm_out[b * NQ + q] = m;
        if (m >= 0) {
            const float v = pen_add(CT[(size_t)m * NQ + q], L - (int)tmat[q]);
            const unsigned long long key = ((unsigned long long)ordered_bits(v) << 32) | (unsigned)q;
            atomicMin(&colkey[m], key);
        }
    }
    __syncthreads();
    if (tid < NG) out[OFF_MQ + (size_t)b * NG + tid] = (float)(unsigned)(colkey[tid] & 0xffffffffull);
}

// ---------------- m-expand: write OM[q][g] = (rm[q]==g) ----------------
// One thread per q; writes its 100-float row (400B, 16B-aligned) as 25 float4 stores.
__global__ __launch_bounds__(256) void m_expand_kernel(
    const int* __restrict__ rm, float* __restrict__ out)
{
    const int b = blockIdx.y;
    const int q = blockIdx.x * 256 + threadIdx.x;
    if (q >= NQ) return;
    const int m = rm[b * NQ + q];
    float4* OM = reinterpret_cast<float4*>(out + OFF_M + ((size_t)b * NQ + q) * NG);
#pragma unroll
    for (int j = 0; j < NG / 4; ++j) {
        const int g0 = j * 4;
        float4 v;
        v.x = (m == g0 + 0) ? 1.0f : 0.0f;
        v.y = (m == g0 + 1) ? 1.0f : 0.0f;
        v.z = (m == g0 + 2) ? 1.0f : 0.0f;
        v.w = (m == g0 + 3) ? 1.0f : 0.0f;
        OM[j] = v;
    }
}

extern "C" void kernel_launch(void* const* d_in, const int* in_sizes, int n_in,
                              void* d_out, int out_size, void* d_ws, size_t ws_size,
                              hipStream_t stream)
{
    const float* l1  = (const float*)d_in[0];
    const float* l2  = (const float*)d_in[1];
    const float* l3  = (const float*)d_in[2];
    const float* pb  = (const float*)d_in[3];
    const float* gbx = (const float*)d_in[4];
    const float* img = (const float*)d_in[5];
    const int*   t1  = (const int*)d_in[6];
    const int*   t2  = (const int*)d_in[7];
    const int*   t3  = (const int*)d_in[8];
    float* out = (float*)d_out;

    char* ws = (char*)d_ws;
    float* costT = (float*)ws;                                   ws += (size_t)NB * NG * NQ * sizeof(float); // 51.2 MB
    int*   rm    = (int*)ws;                                     ws += (size_t)NB * NQ * sizeof(int);
    int*   grc   = (int*)ws;                                     ws += (size_t)NB * NQ * sizeof(int);
    int*   grnew = (int*)ws;                                     ws += (size_t)NB * NQ * sizeof(int);
    uint4* bmws  = (uint4*)ws;                                   ws += (size_t)NB * NQ * sizeof(uint4);
    float* fgws  = (float*)ws;                                   ws += (size_t)NB * NQ * sizeof(float);
    int*   grsl  = (int*)ws;                                     // NB*NG*SLK*4 = 204.8 KB

    // FDT scratch lives in the M-output region (out + OFF_M, 51.2 MB >= 22.5 MB): written by
    // focal_kernel, consumed by cost_kernel, overwritten by m_expand_kernel at the end.
    // (cost_kernel writes the q-major cost output OC = out + OFF_COST directly, via LDS transpose.)
    float* FDT = out + OFF_M;
    float* OC  = out + OFF_COST;

    hipMemsetAsync(grc, 0, (size_t)NB * NQ * sizeof(int), stream);

    dim3 fg((NQ + 63) / 64, NB);
    focal_kernel<<<fg, 256, 0, stream>>>(l1, l2, l3, FDT);

    dim3 mk((NQ + 255) / 256, NB);
    mask_kernel<<<mk, 256, 0, stream>>>(pb, gbx, bmws, fgws);

    dim3 cg((NQ + QB - 1) / QB, NB);
    cost_kernel<<<cg, 256, 0, stream>>>(pb, gbx, img, t1, t2, t3, FDT, bmws, fgws, costT, OC);

    dim3 kg(NG, NB);
    col_topk_kernel<<<kg, 256, 0, stream>>>(pb, gbx, costT, grc, grnew, grsl);

    match_kernel<<<NB, MTH, 0, stream>>>(costT, grc, grnew, grsl, out, rm);

    dim3 wg((NQ + 255) / 256, NB);
    m_expand_kernel<<<wg, 256, 0, stream>>>(rm, out);
}

// Round 9
// 294.856 us; speedup vs baseline: 1.2595x; 1.0633x over previous
//
#include <hip/hip_runtime.h>
#include <math.h>
#include <stdint.h>

#define NB 32
#define NQ 4000
#define NG 100
#define NC1 4
#define NC2 32
#define NC3 8
#define NCT 44   // NC1+NC2+NC3
#define SLK 8    // per-column shortlist depth (exact sorted top-SLK by (cost, q)); dk <= 5 < SLK
#define MTH 512  // match_kernel block size (8 waves -> cheaper barriers than 16)
#define QB  128  // cost_kernel q-rows per block

// output layout (floats): m[B,Q,G] | selected[B,Q] | gt_idx[B,Q] | matched_qidx[B,G] | cost[B,Q,G]
static const size_t OFF_M    = 0;
static const size_t OFF_SEL  = (size_t)NB * NQ * NG;          // 12,800,000
static const size_t OFF_GTI  = OFF_SEL + (size_t)NB * NQ;     // 12,928,000
static const size_t OFF_MQ   = OFF_GTI + (size_t)NB * NQ;     // 13,056,000
static const size_t OFF_COST = OFF_MQ + (size_t)NB * NG;      // 13,059,200

__device__ __forceinline__ float focal_diff(float x) {
    float p   = 1.0f / (1.0f + expf(-x));
    float neg = 0.75f * (p * p) * (-logf(1.0f - p + 1e-8f));
    float pos = 0.25f * ((1.0f - p) * (1.0f - p)) * (-logf(p + 1e-8f));
    return pos - neg;
}

__device__ __forceinline__ unsigned ordered_bits(float f) {
    unsigned u = __float_as_uint(f);
    return (u & 0x80000000u) ? ~u : (u | 0x80000000u);
}

// ---------------- focal kernel: FDT[b][c][q] (c-major) via LDS tile transpose ----------------
// FDT scratch lives in the M-output region (out + OFF_M, 51.2 MB >= 22.5 MB): written here,
// consumed by cost_kernel, overwritten by m_expand_kernel at the very end.
__global__ __launch_bounds__(256) void focal_kernel(
    const float* __restrict__ l1, const float* __restrict__ l2, const float* __restrict__ l3,
    float* __restrict__ FDT)
{
    const int b  = blockIdx.y;
    const int q0 = blockIdx.x * 64;
    const int tid = threadIdx.x;
    __shared__ float tile[64][NCT + 1];   // stride 45 (odd) -> conflict-free column reads

    for (int idx = tid; idx < 64 * NC1; idx += 256) {
        const int qi = idx >> 2, c = idx & 3;
        const int q = q0 + qi;
        if (q < NQ) tile[qi][c] = focal_diff(l1[((size_t)b * NQ + q) * NC1 + c]);
    }
    for (int idx = tid; idx < 64 * NC2; idx += 256) {
        const int qi = idx >> 5, c = idx & 31;
        const int q = q0 + qi;
        if (q < NQ) tile[qi][NC1 + c] = focal_diff(l2[((size_t)b * NQ + q) * NC2 + c]);
    }
    for (int idx = tid; idx < 64 * NC3; idx += 256) {
        const int qi = idx >> 3, c = idx & 7;
        const int q = q0 + qi;
        if (q < NQ) tile[qi][NC1 + NC2 + c] = focal_diff(l3[((size_t)b * NQ + q) * NC3 + c]);
    }
    __syncthreads();

    for (int idx = tid; idx < NCT * 64; idx += 256) {
        const int c = idx >> 6, qi = idx & 63;
        const int q = q0 + qi;
        if (q < NQ) FDT[((size_t)b * NCT + c) * NQ + q] = tile[qi][c];
    }
}

// ---------------- cost kernel (now also does mask): grid (NQ/QB, B) ----------------
// Round-9: mask_kernel fused in. Block holds all 100 gt boxes in LDS (incl. round-tripped
// in_box bounds s_ib and center-radius bounds s_ic, bit-identical arithmetic to the old
// mask_kernel). Each thread (qi = tid&127, hf = tid>>7) covers g in [hf*50, hf*50+50) for
// q = q0+qi: pre-pass computes ib/ic -> local bit-mask bmh + fg-half (exchanged via LDS),
// then the main loop uses them directly. costT (g-major) writes stay lane-coalesced; OC
// (q-major) is written via the padded LDS tile as full contiguous 400B rows (round-8 fix).
__global__ __launch_bounds__(256) void cost_kernel(
    const float* __restrict__ pb, const float* __restrict__ gbx, const float* __restrict__ img,
    const int* __restrict__ t1, const int* __restrict__ t2, const int* __restrict__ t3,
    const float* __restrict__ FDT,
    float* __restrict__ costT, float* __restrict__ outc)
{
    const int b   = blockIdx.y;
    const int q0  = blockIdx.x * QB;
    const int tid = threadIdx.x;
    const int qi  = tid & (QB - 1);
    const int hf  = tid >> 7;            // 0: g in [0,50), 1: g in [50,100)

    __shared__ float s_ng[NG][4];
    __shared__ float s_gx[NG][4];
    __shared__ float s_ab[NG];
    __shared__ int   s_lab[NG][3];
    __shared__ float s_isz[4];
    __shared__ float s_ib[NG][4];        // round-tripped xyxy for in_box
    __shared__ float s_ic[NG][4];        // center-radius bounds [xlo,xhi,ylo,yhi]
    __shared__ short fgh[QB][2];         // per-row fg halves
    __shared__ float tile[QB][NG + 1];   // pad 101 -> 2-way LDS bank alias, free

    if (tid < 4) s_isz[tid] = img[b * 4 + tid];
    if (tid < NG) {
        const int g = tid;
        const float x0 = gbx[((size_t)b * NG + g) * 4 + 0];
        const float y0 = gbx[((size_t)b * NG + g) * 4 + 1];
        const float x1 = gbx[((size_t)b * NG + g) * 4 + 2];
        const float y1 = gbx[((size_t)b * NG + g) * 4 + 3];
        s_gx[g][0] = x0; s_gx[g][1] = y0; s_gx[g][2] = x1; s_gx[g][3] = y1;
        s_ab[g] = (x1 - x0) * (y1 - y0);
        s_ng[g][0] = x0 / img[b * 4 + 0];
        s_ng[g][1] = y0 / img[b * 4 + 1];
        s_ng[g][2] = x1 / img[b * 4 + 2];
        s_ng[g][3] = y1 / img[b * 4 + 3];
        s_lab[g][0] = t1[b * NG + g];
        s_lab[g][1] = NC1 + t2[b * NG + g];
        s_lab[g][2] = NC1 + NC2 + t3[b * NG + g];
        // mask bounds (bit-identical to old mask_kernel)
        const float cx = (x0 + x1) * 0.5f, cy = (y0 + y1) * 0.5f;
        const float w0 = x1 - x0, h0 = y1 - y0;
        const float bx0 = cx - 0.5f * w0, bx1 = cx + 0.5f * w0;
        const float by0 = cy - 0.5f * h0, by1 = cy + 0.5f * h0;
        s_ib[g][0] = bx0; s_ib[g][1] = by0; s_ib[g][2] = bx1; s_ib[g][3] = by1;
        const float w = bx1 - bx0, h = by1 - by0;   // recomputed from round-tripped xyxy
        s_ic[g][0] = cx - 2.5f * w; s_ic[g][1] = cx + 2.5f * w;
        s_ic[g][2] = cy - 2.5f * h; s_ic[g][3] = cy + 2.5f * h;
    }
    __syncthreads();

    const int q = q0 + qi;
    const bool alive = (q < NQ);
    const int gbeg = hf * (NG / 2);

    float4 pv;
    unsigned long long bmh = 0ull;       // bit gl: in_box && in_ctr for g = gbeg+gl
    short fgloc = 0;
    if (alive) {
        pv = reinterpret_cast<const float4*>(pb)[(size_t)b * NQ + q];
        const float ax = (pv.x + pv.z) * 0.5f, ay = (pv.y + pv.w) * 0.5f;
        for (int gl = 0; gl < NG / 2; ++gl) {
            const int g = gbeg + gl;
            const bool ib = (ax > s_ib[g][0]) && (ax < s_ib[g][2]) && (ay > s_ib[g][1]) && (ay < s_ib[g][3]);
            const bool ic = (ax > s_ic[g][0]) && (ax < s_ic[g][1]) && (ay > s_ic[g][2]) && (ay < s_ic[g][3]);
            if (ib || ic) fgloc = 1;
            if (ib && ic) bmh |= (1ull << gl);
        }
    }
    fgh[qi][hf] = fgloc;
    __syncthreads();

    if (alive) {
        const float p0 = pv.x, p1 = pv.y, p2 = pv.z, p3 = pv.w;
        const float areaA = (p2 - p0) * (p3 - p1);
        const float n0 = p0 / s_isz[0], n1 = p1 / s_isz[1], n2 = p2 / s_isz[2], n3 = p3 / s_isz[3];
        const float fgadd = (fgh[qi][0] | fgh[qi][1]) ? 0.0f : 10000.0f;

        const float* F = FDT + (size_t)b * NCT * NQ + q;
        float* ct = costT + (size_t)b * NG * NQ + q;
#pragma unroll 5
        for (int gl = 0; gl < NG / 2; ++gl) {
            const int g = gbeg + gl;
            const float f1 = F[(size_t)s_lab[g][0] * NQ];
            const float f2 = F[(size_t)s_lab[g][1] * NQ];
            const float f3 = F[(size_t)s_lab[g][2] * NQ];
            float cb = fabsf(n0 - s_ng[g][0]);
            cb = cb + fabsf(n1 - s_ng[g][1]);
            cb = cb + fabsf(n2 - s_ng[g][2]);
            cb = cb + fabsf(n3 - s_ng[g][3]);
            const float gx0 = s_gx[g][0], gy0 = s_gx[g][1], gx1 = s_gx[g][2], gy1 = s_gx[g][3];
            const float ltx = fmaxf(p0, gx0), lty = fmaxf(p1, gy0);
            const float rbx = fminf(p2, gx1), rby = fminf(p3, gy1);
            const float iw = fmaxf(rbx - ltx, 0.0f), ih = fmaxf(rby - lty, 0.0f);
            const float inter = iw * ih;
            const float uni = areaA + s_ab[g] - inter;
            const float iou = inter / uni;
            const float ex0 = fminf(p0, gx0), ey0 = fminf(p1, gy0);
            const float ex1 = fmaxf(p2, gx1), ey1 = fmaxf(p3, gy1);
            const float ew = fmaxf(ex1 - ex0, 0.0f), eh = fmaxf(ey1 - ey0, 0.0f);
            const float ea = ew * eh;
            const float giou = iou - (ea - uni) / ea;
            const float cc = (f1 + f2) + f3;
            const bool inbc = (bmh >> gl) & 1ull;
            float cost = cb;
            cost = cost + 0.33333334f * cc;
            cost = cost + (-giou);
            cost = cost + (inbc ? 0.0f : 100.0f);
            cost = cost + fgadd;
            ct[(size_t)g * NQ] = cost;   // g-major: lanes (consec q) coalesced per g
            tile[qi][g] = cost;
        }
    }
    __syncthreads();

    // coalesced q-major OC write: full contiguous rows [q0, q0+nrows) x 100 floats
    const int nrows = (NQ - q0 < QB) ? (NQ - q0) : QB;
    float4* OCb = reinterpret_cast<float4*>(outc + ((size_t)b * NQ + q0) * NG);
    for (int idx = tid; idx < nrows * (NG / 4); idx += 256) {
        const int r = idx / (NG / 4), j = idx - r * (NG / 4);
        float4 v;
        v.x = tile[r][4 * j + 0];
        v.y = tile[r][4 * j + 1];
        v.z = tile[r][4 * j + 2];
        v.w = tile[r][4 * j + 3];
        OCb[(size_t)r * (NG / 4) + j] = v;
    }
}

// ---------------- top-k helpers (validated merge path) ----------------
template <bool MAXSEL>
__device__ __forceinline__ bool better(float av, int ai, float bv, int bi) {
    if (MAXSEL) return (av > bv) || (av == bv && ai < bi);
    else        return (av < bv) || (av == bv && ai < bi);
}

template <bool MAXSEL>
__device__ __forceinline__ void ins5(float (&v)[5], int (&id)[5], float nv, int ni) {
    if (!better<MAXSEL>(nv, ni, v[4], id[4])) return;
    v[4] = nv; id[4] = ni;
#pragma unroll
    for (int j = 4; j > 0; --j) {
        if (better<MAXSEL>(v[j], id[j], v[j - 1], id[j - 1])) {
            float tv = v[j]; v[j] = v[j - 1]; v[j - 1] = tv;
            int   ti = id[j]; id[j] = id[j - 1]; id[j - 1] = ti;
        }
    }
}

template <bool MAXSEL>
__device__ __forceinline__ void merge5(float (&v)[5], int (&id)[5], float (&ov)[5], int (&oi)[5]) {
#pragma unroll
    for (int r = 0; r < 5; ++r) {
        float bv = v[0]; int bi = id[0];
#pragma unroll
        for (int off = 32; off >= 1; off >>= 1) {
            float xv = __shfl_xor(bv, off, 64);
            int   xi = __shfl_xor(bi, off, 64);
            if (better<MAXSEL>(xv, xi, bv, bi)) { bv = xv; bi = xi; }
        }
        ov[r] = bv; oi[r] = bi;
        if (id[0] == bi) {
            v[0] = v[1]; id[0] = id[1];
            v[1] = v[2]; id[1] = id[2];
            v[2] = v[3]; id[2] = id[3];
            v[3] = v[4]; id[3] = id[4];
            v[4] = MAXSEL ? -INFINITY : INFINITY; id[4] = 0x7fffffff;
        }
    }
}

// ---------------- branchless insertion networks (per-lane scan only) ----------------
__device__ __forceinline__ void push_max5i(float (&v)[5], int (&id)[5], float t, int it) {
#pragma unroll
    for (int i = 0; i < 5; ++i) {
        const bool b = t > v[i];
        const float nv = b ? t : v[i];
        const float nt = b ? v[i] : t;
        const int ni  = b ? it : id[i];
        const int nit = b ? id[i] : it;
        v[i] = nv; id[i] = ni; t = nt; it = nit;
    }
}

// ---------------- per-column top-k (4 waves/column) + exact sorted top-8 shortlist ----------------
// Shortlist keys: u64 = (ordered_bits(cost) << 32) | q — u64 '<' == (cost, q) lexicographic.
// Per-lane Batcher sort-16 (63 CE), then 8-round wave arg-min merge (SLK=8; dk <= 5 always,
// since iou <= 1 -> sum of top-5 < 8), then tid0 4-way merge. dk is emitted to grdk and
// seeding is done in match_kernel's LDS — no global atomics, no grc memset dispatch.
#define CHUNK 1000   // NQ / 4

#define CE(i, j) { const unsigned long long _a = kk[i], _b = kk[j]; \
                   const bool _s = _b < _a; \
                   kk[i] = _s ? _b : _a; kk[j] = _s ? _a : _b; }

__global__ __launch_bounds__(256, 2) void col_topk_kernel(
    const float* __restrict__ pb, const float* __restrict__ gbx, const float* __restrict__ costT,
    int* __restrict__ grsl, int* __restrict__ grdk)
{
    const int g = blockIdx.x, b = blockIdx.y;
    const int tid = threadIdx.x, lane = tid & 63, wave = tid >> 6;   // 4 waves

    __shared__ float              s_v[4][5];
    __shared__ int                s_i[4][5];
    __shared__ unsigned long long s_ck[4][SLK];

    const float gx0 = gbx[((size_t)b * NG + g) * 4 + 0];
    const float gy0 = gbx[((size_t)b * NG + g) * 4 + 1];
    const float gx1 = gbx[((size_t)b * NG + g) * 4 + 2];
    const float gy1 = gbx[((size_t)b * NG + g) * 4 + 3];
    const float areaB = (gx1 - gx0) * (gy1 - gy0);
    const float4* PB = reinterpret_cast<const float4*>(pb) + (size_t)b * NQ;
    const float* CT = costT + (size_t)b * NG * NQ + (size_t)g * NQ;

    const int q0 = wave * CHUNK;

    // ---- Phase 1: cost top-8 (min, sorted). Load folded directly into key pack. ----
    {
        unsigned long long kk[16];
#pragma unroll
        for (int i = 0; i < 16; ++i) {
            const bool live = (i < 15) || (lane < 40);   // batch 15 covers lanes 0..39 (CHUNK=1000)
            const int q = q0 + i * 64 + lane;
            const float c = live ? CT[q] : 0.0f;
            kk[i] = live ? ((((unsigned long long)ordered_bits(c)) << 32) | (unsigned)q)
                         : ~0ull;
        }

        // Batcher odd-even mergesort, n=16: 63 compare-exchanges, ascending.
        CE(0,1)  CE(2,3)  CE(4,5)  CE(6,7)  CE(8,9)  CE(10,11) CE(12,13) CE(14,15)
        CE(0,2)  CE(1,3)  CE(4,6)  CE(5,7)  CE(8,10) CE(9,11)  CE(12,14) CE(13,15)
        CE(1,2)  CE(5,6)  CE(9,10) CE(13,14)
        CE(0,4)  CE(1,5)  CE(2,6)  CE(3,7)  CE(8,12) CE(9,13)  CE(10,14) CE(11,15)
        CE(2,4)  CE(3,5)  CE(10,12) CE(11,13)
        CE(1,2)  CE(3,4)  CE(5,6)  CE(9,10) CE(11,12) CE(13,14)
        CE(0,8)  CE(1,9)  CE(2,10) CE(3,11) CE(4,12)  CE(5,13)  CE(6,14)  CE(7,15)
        CE(4,8)  CE(5,9)  CE(6,10) CE(7,11)
        CE(2,4)  CE(3,5)  CE(6,8)  CE(7,9)  CE(10,12) CE(11,13)
        CE(1,2)  CE(3,4)  CE(5,6)  CE(7,8)  CE(9,10)  CE(11,12) CE(13,14)

        // SLK-round wave arg-min merge of sorted lane lists; lane0 writes sorted wave top-SLK.
        for (int r = 0; r < SLK; ++r) {
            unsigned long long bk = kk[0];
#pragma unroll
            for (int off = 32; off >= 1; off >>= 1) {
                const unsigned long long xk = __shfl_xor(bk, off, 64);
                if (xk < bk) bk = xk;
            }
            if (lane == 0) s_ck[wave][r] = bk;
            if (kk[0] == bk) {   // winner advances (keys unique for real entries)
#pragma unroll
                for (int j = 0; j < 15; ++j) kk[j] = kk[j + 1];
                kk[15] = ~0ull;
            }
        }
    }

    // ---- Phase 2: IoU top-5 over this wave's chunk (branchless insert; validated path) ----
    {
        const int q1 = q0 + CHUNK;
        float tv[5]; int ti[5];
#pragma unroll
        for (int k = 0; k < 5; ++k) { tv[k] = -INFINITY; ti[k] = 0x7fffffff; }
        for (int base = q0; base < q1; base += 64) {
            const int q = base + lane;
            if (q < q1) {
                const float4 p = PB[q];
                const float ltx = fmaxf(p.x, gx0), lty = fmaxf(p.y, gy0);
                const float rbx = fminf(p.z, gx1), rby = fminf(p.w, gy1);
                const float iw = fmaxf(rbx - ltx, 0.0f), ih = fmaxf(rby - lty, 0.0f);
                const float inter = iw * ih;
                const float areaA = (p.z - p.x) * (p.w - p.y);
                const float uni = areaA + areaB - inter;
                push_max5i(tv, ti, inter / uni, q);
            }
        }
        float ov[5]; int oi[5];
        merge5<true>(tv, ti, ov, oi);
        if (lane == 0) {
#pragma unroll
            for (int k = 0; k < 5; ++k) { s_v[wave][k] = ov[k]; s_i[wave][k] = oi[k]; }
        }
    }
    __syncthreads();

    if (tid == 0) {
        // dynamic_k from IoU top-5
        float tv[5]; int ti[5];
#pragma unroll
        for (int k = 0; k < 5; ++k) { tv[k] = -INFINITY; ti[k] = 0x7fffffff; }
        for (int w = 0; w < 4; ++w)
#pragma unroll
            for (int k = 0; k < 5; ++k) ins5<true>(tv, ti, s_v[w][k], s_i[w][k]);
        const float s = ((((tv[0] + tv[1]) + tv[2]) + tv[3]) + tv[4]);
        int dk = (int)s;   // trunc toward zero, matches astype(int32); dk <= 5 since iou <= 1
        if (dk < 1) dk = 1;

        // 4-way merge of sorted u64 wave lists -> exact sorted column top-SLK.
        int h0 = 0, h1 = 0, h2 = 0, h3 = 0;
        int* SL = grsl + ((size_t)b * NG + g) * SLK;
        for (int k = 0; k < SLK; ++k) {
            unsigned long long bk = ~0ull; int bw = 0;
            if (h0 < SLK && s_ck[0][h0] < bk) { bk = s_ck[0][h0]; bw = 0; }
            if (h1 < SLK && s_ck[1][h1] < bk) { bk = s_ck[1][h1]; bw = 1; }
            if (h2 < SLK && s_ck[2][h2] < bk) { bk = s_ck[2][h2]; bw = 2; }
            if (h3 < SLK && s_ck[3][h3] < bk) { bk = s_ck[3][h3]; bw = 3; }
            if (bw == 0) h0++; else if (bw == 1) h1++; else if (bw == 2) h2++; else h3++;
            SL[k] = (int)(unsigned)(bk & 0xffffffffull);
        }
        grdk[b * NG + g] = dk;
    }
}

// replicate reference's sequential penalty accumulation rounding
__device__ __forceinline__ float pen_add(float v, int k) {
    while (k-- > 0) v += 100000.0f;
    return v;
}

// ---------------- match kernel: one block per image, incremental worklist version ----------------
// Seeding now done in-LDS from grsl+grdk (no global atomics / memset dispatch): for each column
// g, rc[SL[k]]++ and rnew[SL[k]]=g for k<dk — the rnew multi-writer race is benign exactly as
// the old grnew race (rnew only read when rc==1 -> unique writer). All other logic unchanged
// from the validated round-6 version (worklist, closed-form pen, shortlist fast path, exact
// fallback, 2 barriers/iter).
__global__ __launch_bounds__(MTH) void match_kernel(
    const float* __restrict__ costT, const int* __restrict__ grsl, const int* __restrict__ grdk,
    float* __restrict__ out, int* __restrict__ rm_out)
{
    const int b = blockIdx.x, tid = threadIdx.x;
    const int lane = tid & 63, wave = tid >> 6;   // 8 waves

    __shared__ short              rmatch[NQ];
    __shared__ short              rnew[NQ];
    __shared__ short              tmat[NQ];     // iteration of first match (valid iff rmatch>=0)
    __shared__ int                rc[NQ];
    __shared__ int                colc[NG];
    __shared__ unsigned long long colkey[NG];
    __shared__ short              sl[NG * SLK];
    __shared__ int                sdk[NG];
    __shared__ short              wl[2][1024];  // double-buffered worklist (seed <= 500, later <= NG)
    __shared__ int                wlc[2];
    __shared__ int                flag;

    const float* CT = costT + (size_t)b * NG * NQ;

    if (tid == 0) { wlc[0] = 0; wlc[1] = 0; }
    if (tid < NG) { colc[tid] = 0; sdk[tid] = grdk[b * NG + tid]; }
    for (int q = tid; q < NQ; q += MTH) { rmatch[q] = -1; rc[q] = 0; rnew[q] = 0; }
    for (int i = tid; i < NG * SLK; i += MTH) sl[i] = (short)grsl[(size_t)b * NG * SLK + i];
    __syncthreads();

    // seed rc/rnew from shortlist prefixes (dk <= 5 < SLK)
    if (tid < NG) {
        const int g = tid;
        const int dk = sdk[g];
        for (int k = 0; k < dk; ++k) {
            const int q = (int)sl[g * SLK + k];
            atomicAdd(&rc[q], 1);
            rnew[q] = (short)g;   // benign race: only read when rc==1
        }
    }
    __syncthreads();

    for (int q = tid; q < NQ; q += MTH) {
        if (rc[q] > 0) { const int i = atomicAdd(&wlc[0], 1); wl[0][i] = (short)q; }
    }
    __syncthreads();

    int L = 2000;
    for (int iter = 0; iter < 2000; ++iter) {
        const int p = iter & 1;
        // ---- Phase A: process this iteration's worklist (dedup via atomicExch) ----
        const int n = wlc[p];
        for (int i = tid; i < n; i += MTH) {
            const int q = (int)wl[p][i];
            const int rcq = atomicExch(&rc[q], 0);
            if (rcq == 0) continue;              // duplicate entry already handled
            const int oldm = rmatch[q];
            const int c = rcq + (oldm >= 0 ? 1 : 0);
            int nm;
            if (c == 1) nm = (int)rnew[q];       // rcq>=1 here, so reference takes rnew
            else {
                const int kp = (oldm >= 0) ? (iter - (int)tmat[q]) : 0;
                float bv = INFINITY; nm = 0;
                for (int g = 0; g < NG; ++g) {
                    const float v = pen_add(CT[(size_t)g * NQ + q], kp);
                    if (v < bv) { bv = v; nm = g; }
                }
            }
            rmatch[q] = (short)nm;
            if (oldm < 0) { tmat[q] = (short)iter; atomicAdd(&colc[nm], 1); }
            else if (oldm != nm) { atomicSub(&colc[oldm], 1); atomicAdd(&colc[nm], 1); }
        }
        if (tid == 0) { wlc[p ^ 1] = 0; flag = 0; }   // wl[p^1]/flag untouched by Phase A
        __syncthreads();

        // ---- Phase C: rematch zero columns (direct colc scan; pen here = iter+1 - tmat) ----
        for (int g = wave; g < NG; g += (MTH / 64)) {
            if (colc[g] != 0) continue;
            if (lane == 0) flag = 1;             // benign multi-write, same value
            // shortlist fast path: first (by sorted (cost,q) order) entry with pen==0
            int cand = -1;
            if (lane < SLK) {
                const int qq = (int)sl[g * SLK + lane];
                if (rmatch[qq] < 0) cand = qq;
            }
            const unsigned long long bal = __ballot(cand >= 0);
            int bi;
            if (bal != 0ull) {
                const int src = __ffsll(bal) - 1;
                bi = __shfl(cand, src, 64);
            } else {
                // fallback: exact full scan with pen_add semantics (rare)
                float bv = INFINITY; bi = 0x7fffffff;
                for (int base = 0; base < NQ; base += 64) {
                    const int q = base + lane;
                    if (q < NQ) {
                        const int kp = (rmatch[q] >= 0) ? (iter + 1 - (int)tmat[q]) : 0;
                        const float v = pen_add(CT[(size_t)g * NQ + q], kp);
                        if (v < bv || (v == bv && q < bi)) { bv = v; bi = q; }
                    }
                }
#pragma unroll
                for (int off = 32; off >= 1; off >>= 1) {
                    const float xv = __shfl_xor(bv, off, 64);
                    const int   xi = __shfl_xor(bi, off, 64);
                    if (xv < bv || (xv == bv && xi < bi)) { bv = xv; bi = xi; }
                }
            }
            if (lane == 0) {
                atomicAdd(&rc[bi], 1);
                rnew[bi] = (short)g;             // benign race: only read when count==1
                const int i = atomicAdd(&wlc[p ^ 1], 1);
                wl[p ^ 1][i] = (short)bi;
            }
        }
        __syncthreads();
        if (!flag) { L = iter; break; }
    }

    // outputs: selected, gt_idx, rm; matched_qidx via per-row atomicMin (ordered-float<<32 | q)
    if (tid < NG) colkey[tid] = ~0ull;
    __syncthreads();
    for (int q = tid; q < NQ; q += MTH) {
        const int m = rmatch[q];
        out[OFF_SEL + (size_t)b * NQ + q] = (m >= 0) ? 1.0f : 0.0f;
        out[OFF_GTI + (size_t)b * NQ + q] = (float)(m >= 0 ? m : 0);
        rm_out[b * NQ + q] = m;
        if (m >= 0) {
            const float v = pen_add(CT[(size_t)m * NQ + q], L - (int)tmat[q]);
            const unsigned long long key = ((unsigned long long)ordered_bits(v) << 32) | (unsigned)q;
            atomicMin(&colkey[m], key);
        }
    }
    __syncthreads();
    if (tid < NG) out[OFF_MQ + (size_t)b * NG + tid] = (float)(unsigned)(colkey[tid] & 0xffffffffull);
}

// ---------------- m-expand: write OM[q][g] = (rm[q]==g) ----------------
__global__ __launch_bounds__(256) void m_expand_kernel(
    const int* __restrict__ rm, float* __restrict__ out)
{
    const int b = blockIdx.y;
    const int q = blockIdx.x * 256 + threadIdx.x;
    if (q >= NQ) return;
    const int m = rm[b * NQ + q];
    float4* OM = reinterpret_cast<float4*>(out + OFF_M + ((size_t)b * NQ + q) * NG);
#pragma unroll
    for (int j = 0; j < NG / 4; ++j) {
        const int g0 = j * 4;
        float4 v;
        v.x = (m == g0 + 0) ? 1.0f : 0.0f;
        v.y = (m == g0 + 1) ? 1.0f : 0.0f;
        v.z = (m == g0 + 2) ? 1.0f : 0.0f;
        v.w = (m == g0 + 3) ? 1.0f : 0.0f;
        OM[j] = v;
    }
}

extern "C" void kernel_launch(void* const* d_in, const int* in_sizes, int n_in,
                              void* d_out, int out_size, void* d_ws, size_t ws_size,
                              hipStream_t stream)
{
    const float* l1  = (const float*)d_in[0];
    const float* l2  = (const float*)d_in[1];
    const float* l3  = (const float*)d_in[2];
    const float* pb  = (const float*)d_in[3];
    const float* gbx = (const float*)d_in[4];
    const float* img = (const float*)d_in[5];
    const int*   t1  = (const int*)d_in[6];
    const int*   t2  = (const int*)d_in[7];
    const int*   t3  = (const int*)d_in[8];
    float* out = (float*)d_out;

    char* ws = (char*)d_ws;
    float* costT = (float*)ws;                                   ws += (size_t)NB * NG * NQ * sizeof(float); // 51.2 MB
    int*   rm    = (int*)ws;                                     ws += (size_t)NB * NQ * sizeof(int);
    int*   grsl  = (int*)ws;                                     ws += (size_t)NB * NG * SLK * sizeof(int);
    int*   grdk  = (int*)ws;                                     // NB*NG ints

    // FDT scratch lives in the M-output region (out + OFF_M, 51.2 MB >= 22.5 MB): written by
    // focal_kernel, consumed by cost_kernel, overwritten by m_expand_kernel at the end.
    // cost_kernel writes the q-major cost output OC = out + OFF_COST directly (LDS transpose).
    float* FDT = out + OFF_M;
    float* OC  = out + OFF_COST;

    dim3 fg((NQ + 63) / 64, NB);
    focal_kernel<<<fg, 256, 0, stream>>>(l1, l2, l3, FDT);

    dim3 cg((NQ + QB - 1) / QB, NB);
    cost_kernel<<<cg, 256, 0, stream>>>(pb, gbx, img, t1, t2, t3, FDT, costT, OC);

    dim3 kg(NG, NB);
    col_topk_kernel<<<kg, 256, 0, stream>>>(pb, gbx, costT, grsl, grdk);

    match_kernel<<<NB, MTH, 0, stream>>>(costT, grsl, grdk, out, rm);

    dim3 wg((NQ + 255) / 256, NB);
    m_expand_kernel<<<wg, 256, 0, stream>>>(rm, out);
}

// Round 10
// 269.392 us; speedup vs baseline: 1.3785x; 1.0945x over previous
//
#include <hip/hip_runtime.h>
#include <math.h>
#include <stdint.h>

#define NB 32
#define NQ 4000
#define NG 100
#define NC1 4
#define NC2 32
#define NC3 8
#define NCT 44   // NC1+NC2+NC3
#define SLK 8    // per-column shortlist depth (exact sorted top-SLK by (cost, q)); dk <= 5 < SLK
#define MTH 512  // match_kernel block size (8 waves -> cheaper barriers than 16)
#define QB  64   // cost_kernel q-rows per block (round-10: halved -> LDS 34KB -> 4 blocks/CU)
#define GQ  (NG / 4)   // 25 g per thread-quarter

// output layout (floats): m[B,Q,G] | selected[B,Q] | gt_idx[B,Q] | matched_qidx[B,G] | cost[B,Q,G]
static const size_t OFF_M    = 0;
static const size_t OFF_SEL  = (size_t)NB * NQ * NG;          // 12,800,000
static const size_t OFF_GTI  = OFF_SEL + (size_t)NB * NQ;     // 12,928,000
static const size_t OFF_MQ   = OFF_GTI + (size_t)NB * NQ;     // 13,056,000
static const size_t OFF_COST = OFF_MQ + (size_t)NB * NG;      // 13,059,200

__device__ __forceinline__ float focal_diff(float x) {
    float p   = 1.0f / (1.0f + expf(-x));
    float neg = 0.75f * (p * p) * (-logf(1.0f - p + 1e-8f));
    float pos = 0.25f * ((1.0f - p) * (1.0f - p)) * (-logf(p + 1e-8f));
    return pos - neg;
}

__device__ __forceinline__ unsigned ordered_bits(float f) {
    unsigned u = __float_as_uint(f);
    return (u & 0x80000000u) ? ~u : (u | 0x80000000u);
}

// ---------------- focal kernel: FDT[b][c][q] (c-major) via LDS tile transpose ----------------
// FDT scratch lives in the M-output region (out + OFF_M, 51.2 MB >= 22.5 MB): written here,
// consumed by cost_kernel, overwritten by m_expand_kernel at the very end.
__global__ __launch_bounds__(256) void focal_kernel(
    const float* __restrict__ l1, const float* __restrict__ l2, const float* __restrict__ l3,
    float* __restrict__ FDT)
{
    const int b  = blockIdx.y;
    const int q0 = blockIdx.x * 64;
    const int tid = threadIdx.x;
    __shared__ float tile[64][NCT + 1];   // stride 45 (odd) -> conflict-free column reads

    for (int idx = tid; idx < 64 * NC1; idx += 256) {
        const int qi = idx >> 2, c = idx & 3;
        const int q = q0 + qi;
        if (q < NQ) tile[qi][c] = focal_diff(l1[((size_t)b * NQ + q) * NC1 + c]);
    }
    for (int idx = tid; idx < 64 * NC2; idx += 256) {
        const int qi = idx >> 5, c = idx & 31;
        const int q = q0 + qi;
        if (q < NQ) tile[qi][NC1 + c] = focal_diff(l2[((size_t)b * NQ + q) * NC2 + c]);
    }
    for (int idx = tid; idx < 64 * NC3; idx += 256) {
        const int qi = idx >> 3, c = idx & 7;
        const int q = q0 + qi;
        if (q < NQ) tile[qi][NC1 + NC2 + c] = focal_diff(l3[((size_t)b * NQ + q) * NC3 + c]);
    }
    __syncthreads();

    for (int idx = tid; idx < NCT * 64; idx += 256) {
        const int c = idx >> 6, qi = idx & 63;
        const int q = q0 + qi;
        if (q < NQ) FDT[((size_t)b * NCT + c) * NQ + q] = tile[qi][c];
    }
}

// ---------------- cost kernel (with fused mask): grid (NQ/QB, B) ----------------
// Round-10: QB 128->64 and g split into QUARTERS (hf = tid>>6 in 0..3, 25 g each). The
// transpose tile halves to 64x101 (25.9 KB), total LDS ~34.4 KB -> 4 blocks/CU (16 waves/CU,
// 2x round-9 occupancy) — round-9 counters showed 60.4 KB LDS capped us at 2 blocks/CU and
// the kernel was latency-bound at 2 waves/SIMD. Mask pre-pass, costT (g-major, lane-coalesced)
// and OC (q-major via padded LDS tile, full contiguous 400B rows) are structurally unchanged.
__global__ __launch_bounds__(256) void cost_kernel(
    const float* __restrict__ pb, const float* __restrict__ gbx, const float* __restrict__ img,
    const int* __restrict__ t1, const int* __restrict__ t2, const int* __restrict__ t3,
    const float* __restrict__ FDT,
    float* __restrict__ costT, float* __restrict__ outc)
{
    const int b   = blockIdx.y;
    const int q0  = blockIdx.x * QB;
    const int tid = threadIdx.x;
    const int qi  = tid & (QB - 1);
    const int hf  = tid >> 6;            // quarter: g in [hf*25, hf*25+25)

    __shared__ float s_ng[NG][4];
    __shared__ float s_gx[NG][4];
    __shared__ float s_ab[NG];
    __shared__ int   s_lab[NG][3];
    __shared__ float s_isz[4];
    __shared__ float s_ib[NG][4];        // round-tripped xyxy for in_box
    __shared__ float s_ic[NG][4];        // center-radius bounds [xlo,xhi,ylo,yhi]
    __shared__ short fgh[QB][4];         // per-row fg quarters
    __shared__ float tile[QB][NG + 1];   // pad 101 -> 2-way LDS bank alias, free

    if (tid < 4) s_isz[tid] = img[b * 4 + tid];
    if (tid < NG) {
        const int g = tid;
        const float x0 = gbx[((size_t)b * NG + g) * 4 + 0];
        const float y0 = gbx[((size_t)b * NG + g) * 4 + 1];
        const float x1 = gbx[((size_t)b * NG + g) * 4 + 2];
        const float y1 = gbx[((size_t)b * NG + g) * 4 + 3];
        s_gx[g][0] = x0; s_gx[g][1] = y0; s_gx[g][2] = x1; s_gx[g][3] = y1;
        s_ab[g] = (x1 - x0) * (y1 - y0);
        s_ng[g][0] = x0 / img[b * 4 + 0];
        s_ng[g][1] = y0 / img[b * 4 + 1];
        s_ng[g][2] = x1 / img[b * 4 + 2];
        s_ng[g][3] = y1 / img[b * 4 + 3];
        s_lab[g][0] = t1[b * NG + g];
        s_lab[g][1] = NC1 + t2[b * NG + g];
        s_lab[g][2] = NC1 + NC2 + t3[b * NG + g];
        // mask bounds (bit-identical to the original mask_kernel)
        const float cx = (x0 + x1) * 0.5f, cy = (y0 + y1) * 0.5f;
        const float w0 = x1 - x0, h0 = y1 - y0;
        const float bx0 = cx - 0.5f * w0, bx1 = cx + 0.5f * w0;
        const float by0 = cy - 0.5f * h0, by1 = cy + 0.5f * h0;
        s_ib[g][0] = bx0; s_ib[g][1] = by0; s_ib[g][2] = bx1; s_ib[g][3] = by1;
        const float w = bx1 - bx0, h = by1 - by0;   // recomputed from round-tripped xyxy
        s_ic[g][0] = cx - 2.5f * w; s_ic[g][1] = cx + 2.5f * w;
        s_ic[g][2] = cy - 2.5f * h; s_ic[g][3] = cy + 2.5f * h;
    }
    __syncthreads();

    const int q = q0 + qi;
    const bool alive = (q < NQ);
    const int gbeg = hf * GQ;

    float4 pv;
    unsigned bmh = 0u;                   // bit gl: in_box && in_ctr for g = gbeg+gl (25 bits)
    short fgloc = 0;
    if (alive) {
        pv = reinterpret_cast<const float4*>(pb)[(size_t)b * NQ + q];
        const float ax = (pv.x + pv.z) * 0.5f, ay = (pv.y + pv.w) * 0.5f;
        for (int gl = 0; gl < GQ; ++gl) {
            const int g = gbeg + gl;
            const bool ib = (ax > s_ib[g][0]) && (ax < s_ib[g][2]) && (ay > s_ib[g][1]) && (ay < s_ib[g][3]);
            const bool ic = (ax > s_ic[g][0]) && (ax < s_ic[g][1]) && (ay > s_ic[g][2]) && (ay < s_ic[g][3]);
            if (ib || ic) fgloc = 1;
            if (ib && ic) bmh |= (1u << gl);
        }
    }
    fgh[qi][hf] = fgloc;
    __syncthreads();

    if (alive) {
        const float p0 = pv.x, p1 = pv.y, p2 = pv.z, p3 = pv.w;
        const float areaA = (p2 - p0) * (p3 - p1);
        const float n0 = p0 / s_isz[0], n1 = p1 / s_isz[1], n2 = p2 / s_isz[2], n3 = p3 / s_isz[3];
        const float fgadd = (fgh[qi][0] | fgh[qi][1] | fgh[qi][2] | fgh[qi][3]) ? 0.0f : 10000.0f;

        const float* F = FDT + (size_t)b * NCT * NQ + q;
        float* ct = costT + (size_t)b * NG * NQ + q;
#pragma unroll 5
        for (int gl = 0; gl < GQ; ++gl) {
            const int g = gbeg + gl;
            const float f1 = F[(size_t)s_lab[g][0] * NQ];
            const float f2 = F[(size_t)s_lab[g][1] * NQ];
            const float f3 = F[(size_t)s_lab[g][2] * NQ];
            float cb = fabsf(n0 - s_ng[g][0]);
            cb = cb + fabsf(n1 - s_ng[g][1]);
            cb = cb + fabsf(n2 - s_ng[g][2]);
            cb = cb + fabsf(n3 - s_ng[g][3]);
            const float gx0 = s_gx[g][0], gy0 = s_gx[g][1], gx1 = s_gx[g][2], gy1 = s_gx[g][3];
            const float ltx = fmaxf(p0, gx0), lty = fmaxf(p1, gy0);
            const float rbx = fminf(p2, gx1), rby = fminf(p3, gy1);
            const float iw = fmaxf(rbx - ltx, 0.0f), ih = fmaxf(rby - lty, 0.0f);
            const float inter = iw * ih;
            const float uni = areaA + s_ab[g] - inter;
            const float iou = inter / uni;
            const float ex0 = fminf(p0, gx0), ey0 = fminf(p1, gy0);
            const float ex1 = fmaxf(p2, gx1), ey1 = fmaxf(p3, gy1);
            const float ew = fmaxf(ex1 - ex0, 0.0f), eh = fmaxf(ey1 - ey0, 0.0f);
            const float ea = ew * eh;
            const float giou = iou - (ea - uni) / ea;
            const float cc = (f1 + f2) + f3;
            const bool inbc = (bmh >> gl) & 1u;
            float cost = cb;
            cost = cost + 0.33333334f * cc;
            cost = cost + (-giou);
            cost = cost + (inbc ? 0.0f : 100.0f);
            cost = cost + fgadd;
            ct[(size_t)g * NQ] = cost;   // g-major: lanes (consec q) coalesced per g
            tile[qi][g] = cost;
        }
    }
    __syncthreads();

    // coalesced q-major OC write: full contiguous rows [q0, q0+nrows) x 100 floats
    const int nrows = (NQ - q0 < QB) ? (NQ - q0) : QB;
    float4* OCb = reinterpret_cast<float4*>(outc + ((size_t)b * NQ + q0) * NG);
    for (int idx = tid; idx < nrows * (NG / 4); idx += 256) {
        const int r = idx / (NG / 4), j = idx - r * (NG / 4);
        float4 v;
        v.x = tile[r][4 * j + 0];
        v.y = tile[r][4 * j + 1];
        v.z = tile[r][4 * j + 2];
        v.w = tile[r][4 * j + 3];
        OCb[(size_t)r * (NG / 4) + j] = v;
    }
}

// ---------------- top-k helpers (validated merge path) ----------------
template <bool MAXSEL>
__device__ __forceinline__ bool better(float av, int ai, float bv, int bi) {
    if (MAXSEL) return (av > bv) || (av == bv && ai < bi);
    else        return (av < bv) || (av == bv && ai < bi);
}

template <bool MAXSEL>
__device__ __forceinline__ void ins5(float (&v)[5], int (&id)[5], float nv, int ni) {
    if (!better<MAXSEL>(nv, ni, v[4], id[4])) return;
    v[4] = nv; id[4] = ni;
#pragma unroll
    for (int j = 4; j > 0; --j) {
        if (better<MAXSEL>(v[j], id[j], v[j - 1], id[j - 1])) {
            float tv = v[j]; v[j] = v[j - 1]; v[j - 1] = tv;
            int   ti = id[j]; id[j] = id[j - 1]; id[j - 1] = ti;
        }
    }
}

template <bool MAXSEL>
__device__ __forceinline__ void merge5(float (&v)[5], int (&id)[5], float (&ov)[5], int (&oi)[5]) {
#pragma unroll
    for (int r = 0; r < 5; ++r) {
        float bv = v[0]; int bi = id[0];
#pragma unroll
        for (int off = 32; off >= 1; off >>= 1) {
            float xv = __shfl_xor(bv, off, 64);
            int   xi = __shfl_xor(bi, off, 64);
            if (better<MAXSEL>(xv, xi, bv, bi)) { bv = xv; bi = xi; }
        }
        ov[r] = bv; oi[r] = bi;
        if (id[0] == bi) {
            v[0] = v[1]; id[0] = id[1];
            v[1] = v[2]; id[1] = id[2];
            v[2] = v[3]; id[2] = id[3];
            v[3] = v[4]; id[3] = id[4];
            v[4] = MAXSEL ? -INFINITY : INFINITY; id[4] = 0x7fffffff;
        }
    }
}

// ---------------- branchless insertion networks (per-lane scan only) ----------------
__device__ __forceinline__ void push_max5i(float (&v)[5], int (&id)[5], float t, int it) {
#pragma unroll
    for (int i = 0; i < 5; ++i) {
        const bool b = t > v[i];
        const float nv = b ? t : v[i];
        const float nt = b ? v[i] : t;
        const int ni  = b ? it : id[i];
        const int nit = b ? id[i] : it;
        v[i] = nv; id[i] = ni; t = nt; it = nit;
    }
}

// ---------------- per-column top-k (4 waves/column) + exact sorted top-8 shortlist ----------------
// Shortlist keys: u64 = (ordered_bits(cost) << 32) | q — u64 '<' == (cost, q) lexicographic.
// Per-lane Batcher sort-16 (63 CE), then 8-round wave arg-min merge (SLK=8; dk <= 5 always,
// since iou <= 1 -> sum of top-5 < 8), then tid0 4-way merge. dk emitted to grdk; seeding is
// done in match_kernel's LDS — no global atomics, no memset dispatch.
#define CHUNK 1000   // NQ / 4

#define CE(i, j) { const unsigned long long _a = kk[i], _b = kk[j]; \
                   const bool _s = _b < _a; \
                   kk[i] = _s ? _b : _a; kk[j] = _s ? _a : _b; }

__global__ __launch_bounds__(256, 2) void col_topk_kernel(
    const float* __restrict__ pb, const float* __restrict__ gbx, const float* __restrict__ costT,
    int* __restrict__ grsl, int* __restrict__ grdk)
{
    const int g = blockIdx.x, b = blockIdx.y;
    const int tid = threadIdx.x, lane = tid & 63, wave = tid >> 6;   // 4 waves

    __shared__ float              s_v[4][5];
    __shared__ int                s_i[4][5];
    __shared__ unsigned long long s_ck[4][SLK];

    const float gx0 = gbx[((size_t)b * NG + g) * 4 + 0];
    const float gy0 = gbx[((size_t)b * NG + g) * 4 + 1];
    const float gx1 = gbx[((size_t)b * NG + g) * 4 + 2];
    const float gy1 = gbx[((size_t)b * NG + g) * 4 + 3];
    const float areaB = (gx1 - gx0) * (gy1 - gy0);
    const float4* PB = reinterpret_cast<const float4*>(pb) + (size_t)b * NQ;
    const float* CT = costT + (size_t)b * NG * NQ + (size_t)g * NQ;

    const int q0 = wave * CHUNK;

    // ---- Phase 1: cost top-8 (min, sorted). Load folded directly into key pack. ----
    {
        unsigned long long kk[16];
#pragma unroll
        for (int i = 0; i < 16; ++i) {
            const bool live = (i < 15) || (lane < 40);   // batch 15 covers lanes 0..39 (CHUNK=1000)
            const int q = q0 + i * 64 + lane;
            const float c = live ? CT[q] : 0.0f;
            kk[i] = live ? ((((unsigned long long)ordered_bits(c)) << 32) | (unsigned)q)
                         : ~0ull;
        }

        // Batcher odd-even mergesort, n=16: 63 compare-exchanges, ascending.
        CE(0,1)  CE(2,3)  CE(4,5)  CE(6,7)  CE(8,9)  CE(10,11) CE(12,13) CE(14,15)
        CE(0,2)  CE(1,3)  CE(4,6)  CE(5,7)  CE(8,10) CE(9,11)  CE(12,14) CE(13,15)
        CE(1,2)  CE(5,6)  CE(9,10) CE(13,14)
        CE(0,4)  CE(1,5)  CE(2,6)  CE(3,7)  CE(8,12) CE(9,13)  CE(10,14) CE(11,15)
        CE(2,4)  CE(3,5)  CE(10,12) CE(11,13)
        CE(1,2)  CE(3,4)  CE(5,6)  CE(9,10) CE(11,12) CE(13,14)
        CE(0,8)  CE(1,9)  CE(2,10) CE(3,11) CE(4,12)  CE(5,13)  CE(6,14)  CE(7,15)
        CE(4,8)  CE(5,9)  CE(6,10) CE(7,11)
        CE(2,4)  CE(3,5)  CE(6,8)  CE(7,9)  CE(10,12) CE(11,13)
        CE(1,2)  CE(3,4)  CE(5,6)  CE(7,8)  CE(9,10)  CE(11,12) CE(13,14)

        // SLK-round wave arg-min merge of sorted lane lists; lane0 writes sorted wave top-SLK.
        for (int r = 0; r < SLK; ++r) {
            unsigned long long bk = kk[0];
#pragma unroll
            for (int off = 32; off >= 1; off >>= 1) {
                const unsigned long long xk = __shfl_xor(bk, off, 64);
                if (xk < bk) bk = xk;
            }
            if (lane == 0) s_ck[wave][r] = bk;
            if (kk[0] == bk) {   // winner advances (keys unique for real entries)
#pragma unroll
                for (int j = 0; j < 15; ++j) kk[j] = kk[j + 1];
                kk[15] = ~0ull;
            }
        }
    }

    // ---- Phase 2: IoU top-5 over this wave's chunk (branchless insert; validated path) ----
    {
        const int q1 = q0 + CHUNK;
        float tv[5]; int ti[5];
#pragma unroll
        for (int k = 0; k < 5; ++k) { tv[k] = -INFINITY; ti[k] = 0x7fffffff; }
        for (int base = q0; base < q1; base += 64) {
            const int q = base + lane;
            if (q < q1) {
                const float4 p = PB[q];
                const float ltx = fmaxf(p.x, gx0), lty = fmaxf(p.y, gy0);
                const float rbx = fminf(p.z, gx1), rby = fminf(p.w, gy1);
                const float iw = fmaxf(rbx - ltx, 0.0f), ih = fmaxf(rby - lty, 0.0f);
                const float inter = iw * ih;
                const float areaA = (p.z - p.x) * (p.w - p.y);
                const float uni = areaA + areaB - inter;
                push_max5i(tv, ti, inter / uni, q);
            }
        }
        float ov[5]; int oi[5];
        merge5<true>(tv, ti, ov, oi);
        if (lane == 0) {
#pragma unroll
            for (int k = 0; k < 5; ++k) { s_v[wave][k] = ov[k]; s_i[wave][k] = oi[k]; }
        }
    }
    __syncthreads();

    if (tid == 0) {
        // dynamic_k from IoU top-5
        float tv[5]; int ti[5];
#pragma unroll
        for (int k = 0; k < 5; ++k) { tv[k] = -INFINITY; ti[k] = 0x7fffffff; }
        for (int w = 0; w < 4; ++w)
#pragma unroll
            for (int k = 0; k < 5; ++k) ins5<true>(tv, ti, s_v[w][k], s_i[w][k]);
        const float s = ((((tv[0] + tv[1]) + tv[2]) + tv[3]) + tv[4]);
        int dk = (int)s;   // trunc toward zero, matches astype(int32); dk <= 5 since iou <= 1
        if (dk < 1) dk = 1;

        // 4-way merge of sorted u64 wave lists -> exact sorted column top-SLK.
        int h0 = 0, h1 = 0, h2 = 0, h3 = 0;
        int* SL = grsl + ((size_t)b * NG + g) * SLK;
        for (int k = 0; k < SLK; ++k) {
            unsigned long long bk = ~0ull; int bw = 0;
            if (h0 < SLK && s_ck[0][h0] < bk) { bk = s_ck[0][h0]; bw = 0; }
            if (h1 < SLK && s_ck[1][h1] < bk) { bk = s_ck[1][h1]; bw = 1; }
            if (h2 < SLK && s_ck[2][h2] < bk) { bk = s_ck[2][h2]; bw = 2; }
            if (h3 < SLK && s_ck[3][h3] < bk) { bk = s_ck[3][h3]; bw = 3; }
            if (bw == 0) h0++; else if (bw == 1) h1++; else if (bw == 2) h2++; else h3++;
            SL[k] = (int)(unsigned)(bk & 0xffffffffull);
        }
        grdk[b * NG + g] = dk;
    }
}

// replicate reference's sequential penalty accumulation rounding
__device__ __forceinline__ float pen_add(float v, int k) {
    while (k-- > 0) v += 100000.0f;
    return v;
}

// ---------------- match kernel: one block per image, incremental worklist version ----------------
// Seeding done in-LDS from grsl+grdk (rnew multi-writer race benign: only read when rc==1 ->
// unique writer). Worklist, closed-form pen, shortlist fast path, exact fallback, 2 barriers
// per iteration — all as validated in rounds 3-9.
__global__ __launch_bounds__(MTH) void match_kernel(
    const float* __restrict__ costT, const int* __restrict__ grsl, const int* __restrict__ grdk,
    float* __restrict__ out, int* __restrict__ rm_out)
{
    const int b = blockIdx.x, tid = threadIdx.x;
    const int lane = tid & 63, wave = tid >> 6;   // 8 waves

    __shared__ short              rmatch[NQ];
    __shared__ short              rnew[NQ];
    __shared__ short              tmat[NQ];     // iteration of first match (valid iff rmatch>=0)
    __shared__ int                rc[NQ];
    __shared__ int                colc[NG];
    __shared__ unsigned long long colkey[NG];
    __shared__ short              sl[NG * SLK];
    __shared__ int                sdk[NG];
    __shared__ short              wl[2][1024];  // double-buffered worklist (seed <= 500, later <= NG)
    __shared__ int                wlc[2];
    __shared__ int                flag;

    const float* CT = costT + (size_t)b * NG * NQ;

    if (tid == 0) { wlc[0] = 0; wlc[1] = 0; }
    if (tid < NG) { colc[tid] = 0; sdk[tid] = grdk[b * NG + tid]; }
    for (int q = tid; q < NQ; q += MTH) { rmatch[q] = -1; rc[q] = 0; rnew[q] = 0; }
    for (int i = tid; i < NG * SLK; i += MTH) sl[i] = (short)grsl[(size_t)b * NG * SLK + i];
    __syncthreads();

    // seed rc/rnew from shortlist prefixes (dk <= 5 < SLK)
    if (tid < NG) {
        const int g = tid;
        const int dk = sdk[g];
        for (int k = 0; k < dk; ++k) {
            const int q = (int)sl[g * SLK + k];
            atomicAdd(&rc[q], 1);
            rnew[q] = (short)g;   // benign race: only read when rc==1
        }
    }
    __syncthreads();

    for (int q = tid; q < NQ; q += MTH) {
        if (rc[q] > 0) { const int i = atomicAdd(&wlc[0], 1); wl[0][i] = (short)q; }
    }
    __syncthreads();

    int L = 2000;
    for (int iter = 0; iter < 2000; ++iter) {
        const int p = iter & 1;
        // ---- Phase A: process this iteration's worklist (dedup via atomicExch) ----
        const int n = wlc[p];
        for (int i = tid; i < n; i += MTH) {
            const int q = (int)wl[p][i];
            const int rcq = atomicExch(&rc[q], 0);
            if (rcq == 0) continue;              // duplicate entry already handled
            const int oldm = rmatch[q];
            const int c = rcq + (oldm >= 0 ? 1 : 0);
            int nm;
            if (c == 1) nm = (int)rnew[q];       // rcq>=1 here, so reference takes rnew
            else {
                const int kp = (oldm >= 0) ? (iter - (int)tmat[q]) : 0;
                float bv = INFINITY; nm = 0;
                for (int g = 0; g < NG; ++g) {
                    const float v = pen_add(CT[(size_t)g * NQ + q], kp);
                    if (v < bv) { bv = v; nm = g; }
                }
            }
            rmatch[q] = (short)nm;
            if (oldm < 0) { tmat[q] = (short)iter; atomicAdd(&colc[nm], 1); }
            else if (oldm != nm) { atomicSub(&colc[oldm], 1); atomicAdd(&colc[nm], 1); }
        }
        if (tid == 0) { wlc[p ^ 1] = 0; flag = 0; }   // wl[p^1]/flag untouched by Phase A
        __syncthreads();

        // ---- Phase C: rematch zero columns (direct colc scan; pen here = iter+1 - tmat) ----
        for (int g = wave; g < NG; g += (MTH / 64)) {
            if (colc[g] != 0) continue;
            if (lane == 0) flag = 1;             // benign multi-write, same value
            // shortlist fast path: first (by sorted (cost,q) order) entry with pen==0
            int cand = -1;
            if (lane < SLK) {
                const int qq = (int)sl[g * SLK + lane];
                if (rmatch[qq] < 0) cand = qq;
            }
            const unsigned long long bal = __ballot(cand >= 0);
            int bi;
            if (bal != 0ull) {
                const int src = __ffsll(bal) - 1;
                bi = __shfl(cand, src, 64);
            } else {
                // fallback: exact full scan with pen_add semantics (rare)
                float bv = INFINITY; bi = 0x7fffffff;
                for (int base = 0; base < NQ; base += 64) {
                    const int q = base + lane;
                    if (q < NQ) {
                        const int kp = (rmatch[q] >= 0) ? (iter + 1 - (int)tmat[q]) : 0;
                        const float v = pen_add(CT[(size_t)g * NQ + q], kp);
                        if (v < bv || (v == bv && q < bi)) { bv = v; bi = q; }
                    }
                }
#pragma unroll
                for (int off = 32; off >= 1; off >>= 1) {
                    const float xv = __shfl_xor(bv, off, 64);
                    const int   xi = __shfl_xor(bi, off, 64);
                    if (xv < bv || (xv == bv && xi < bi)) { bv = xv; bi = xi; }
                }
            }
            if (lane == 0) {
                atomicAdd(&rc[bi], 1);
                rnew[bi] = (short)g;             // benign race: only read when count==1
                const int i = atomicAdd(&wlc[p ^ 1], 1);
                wl[p ^ 1][i] = (short)bi;
            }
        }
        __syncthreads();
        if (!flag) { L = iter; break; }
    }

    // outputs: selected, gt_idx, rm; matched_qidx via per-row atomicMin (ordered-float<<32 | q)
    if (tid < NG) colkey[tid] = ~0ull;
    __syncthreads();
    for (int q = tid; q < NQ; q += MTH) {
        const int m = rmatch[q];
        out[OFF_SEL + (size_t)b * NQ + q] = (m >= 0) ? 1.0f : 0.0f;
        out[OFF_GTI + (size_t)b * NQ + q] = (float)(m >= 0 ? m : 0);
        rm_out[b * NQ + q] = m;
        if (m >= 0) {
            const float v = pen_add(CT[(size_t)m * NQ + q], L - (int)tmat[q]);
            const unsigned long long key = ((unsigned long long)ordered_bits(v) << 32) | (unsigned)q;
            atomicMin(&colkey[m], key);
        }
    }
    __syncthreads();
    if (tid < NG) out[OFF_MQ + (size_t)b * NG + tid] = (float)(unsigned)(colkey[tid] & 0xffffffffull);
}

// ---------------- m-expand: write OM[q][g] = (rm[q]==g) ----------------
__global__ __launch_bounds__(256) void m_expand_kernel(
    const int* __restrict__ rm, float* __restrict__ out)
{
    const int b = blockIdx.y;
    const int q = blockIdx.x * 256 + threadIdx.x;
    if (q >= NQ) return;
    const int m = rm[b * NQ + q];
    float4* OM = reinterpret_cast<float4*>(out + OFF_M + ((size_t)b * NQ + q) * NG);
#pragma unroll
    for (int j = 0; j < NG / 4; ++j) {
        const int g0 = j * 4;
        float4 v;
        v.x = (m == g0 + 0) ? 1.0f : 0.0f;
        v.y = (m == g0 + 1) ? 1.0f : 0.0f;
        v.z = (m == g0 + 2) ? 1.0f : 0.0f;
        v.w = (m == g0 + 3) ? 1.0f : 0.0f;
        OM[j] = v;
    }
}

extern "C" void kernel_launch(void* const* d_in, const int* in_sizes, int n_in,
                              void* d_out, int out_size, void* d_ws, size_t ws_size,
                              hipStream_t stream)
{
    const float* l1  = (const float*)d_in[0];
    const float* l2  = (const float*)d_in[1];
    const float* l3  = (const float*)d_in[2];
    const float* pb  = (const float*)d_in[3];
    const float* gbx = (const float*)d_in[4];
    const float* img = (const float*)d_in[5];
    const int*   t1  = (const int*)d_in[6];
    const int*   t2  = (const int*)d_in[7];
    const int*   t3  = (const int*)d_in[8];
    float* out = (float*)d_out;

    char* ws = (char*)d_ws;
    float* costT = (float*)ws;                                   ws += (size_t)NB * NG * NQ * sizeof(float); // 51.2 MB
    int*   rm    = (int*)ws;                                     ws += (size_t)NB * NQ * sizeof(int);
    int*   grsl  = (int*)ws;                                     ws += (size_t)NB * NG * SLK * sizeof(int);
    int*   grdk  = (int*)ws;                                     // NB*NG ints

    // FDT scratch lives in the M-output region (out + OFF_M, 51.2 MB >= 22.5 MB): written by
    // focal_kernel, consumed by cost_kernel, overwritten by m_expand_kernel at the end.
    // cost_kernel writes the q-major cost output OC = out + OFF_COST directly (LDS transpose).
    float* FDT = out + OFF_M;
    float* OC  = out + OFF_COST;

    dim3 fg((NQ + 63) / 64, NB);
    focal_kernel<<<fg, 256, 0, stream>>>(l1, l2, l3, FDT);

    dim3 cg((NQ + QB - 1) / QB, NB);
    cost_kernel<<<cg, 256, 0, stream>>>(pb, gbx, img, t1, t2, t3, FDT, costT, OC);

    dim3 kg(NG, NB);
    col_topk_kernel<<<kg, 256, 0, stream>>>(pb, gbx, costT, grsl, grdk);

    match_kernel<<<NB, MTH, 0, stream>>>(costT, grsl, grdk, out, rm);

    dim3 wg((NQ + 255) / 256, NB);
    m_expand_kernel<<<wg, 256, 0, stream>>>(rm, out);
}